// Round 12
// baseline (862.555 us; speedup 1.0000x reference)
//
#include <hip/hip_runtime.h>
#include <math.h>

typedef __attribute__((ext_vector_type(4))) float f32x4;
typedef __attribute__((ext_vector_type(4))) unsigned int u32x4;
typedef __attribute__((ext_vector_type(8))) unsigned short u16x8;
typedef __attribute__((ext_vector_type(8))) __bf16 bf16x8;
typedef unsigned short ushort_t;

#define H_DIM 2048
#define T_TOK 2048
#define NEXP 16
#define I_DIM 1408
#define I2_DIM 2816
#define IS_DIM 5632
#define MAXROWS 6144

static __device__ __forceinline__ unsigned short f2bf(float f){
  union { float f; unsigned u; } v; v.f = f;
  unsigned r = v.u + 0x7FFFu + ((v.u >> 16) & 1u);
  return (unsigned short)(r >> 16);
}
static __device__ __forceinline__ float bf2f(unsigned short h){
  union { unsigned u; float f; } v; v.u = ((unsigned)h) << 16;
  return v.f;
}
static __device__ __forceinline__ float silu_f(float x){ return x / (1.f + __expf(-x)); }

// async global->LDS, 16B/lane; LDS dest wave-uniform base, HW adds lane*16.
static __device__ __forceinline__ void gld16(const ushort_t* g, ushort_t* l){
  __builtin_amdgcn_global_load_lds(
      (const __attribute__((address_space(1))) unsigned int*)g,
      (__attribute__((address_space(3))) unsigned int*)l, 16, 0, 0);
}

// inline-asm ds_read_b128: opaque to LDS-DMA alias tracking (no forced vmcnt drain).
static __device__ __forceinline__ bf16x8 dsr128(unsigned byte_off){
  u32x4 r;
  asm volatile("ds_read_b128 %0, %1" : "=v"(r) : "v"(byte_off));
  return __builtin_bit_cast(bf16x8, r);
}

// ---------------- cast x -> bf16 ----------------
__global__ void cast_bf16_k(const float* __restrict__ in, ushort_t* __restrict__ out){
  long i = ((long)blockIdx.x * 256 + threadIdx.x) * 8;
  f32x4 a = *(const f32x4*)&in[i];
  f32x4 b = *(const f32x4*)&in[i + 4];
  union { ushort_t s[8]; u32x4 v; } pk;
  #pragma unroll
  for (int j = 0; j < 4; j++){ pk.s[j] = f2bf(a[j]); pk.s[j+4] = f2bf(b[j]); }
  *(u32x4*)&out[i] = pk.v;
}

// ------- transpose + cast: in[z][K][N] fp32 -> out[z][N][K] bf16, 64x64 tiles ------
__global__ void transpose_cast_k(const float* __restrict__ in, ushort_t* __restrict__ out,
                                 int K, int N){
  long zo = (long)blockIdx.z * K * N;
  in += zo; out += zo;
  __shared__ float tl[64][65];
  int n0 = blockIdx.x * 64, k0 = blockIdx.y * 64;
  int tid = threadIdx.x;           // 256
  int lr = tid >> 2;               // source row (k)
  int lv = (tid & 3) * 4;
  #pragma unroll
  for (int j = 0; j < 4; j++){
    int col = lv + j * 16;
    f32x4 v = *(const f32x4*)&in[(long)(k0 + lr) * N + n0 + col];
    tl[lr][col + 0] = v[0]; tl[lr][col + 1] = v[1];
    tl[lr][col + 2] = v[2]; tl[lr][col + 3] = v[3];
  }
  __syncthreads();
  int nl = tid >> 3;
  int kc = (tid & 7) * 8;
  #pragma unroll
  for (int it = 0; it < 2; it++){
    int n = nl + it * 32;
    union { ushort_t s[8]; u32x4 v; } pk;
    #pragma unroll
    for (int j = 0; j < 8; j++) pk.s[j] = f2bf(tl[kc + j][n]);
    *(u32x4*)&out[(long)(n0 + n) * K + k0 + kc] = pk.v;
  }
}

// ---------------- router ----------------
__global__ void router_k(const float* __restrict__ x, const float* __restrict__ rw,
                         const float* __restrict__ sgw, float* __restrict__ logits,
                         int* __restrict__ counts, int* __restrict__ lists,
                         float* __restrict__ probs, float* __restrict__ sgmul){
  int wid = threadIdx.x >> 6, lane = threadIdx.x & 63;
  int t = blockIdx.x * 4 + wid;
  const float* xr = x + (long)t * H_DIM;
  float acc[17];
  #pragma unroll
  for (int e = 0; e < 17; e++) acc[e] = 0.f;
  for (int h0 = lane * 4; h0 < H_DIM; h0 += 256){
    f32x4 xv = *(const f32x4*)&xr[h0];
    #pragma unroll
    for (int i = 0; i < 4; i++){
      float xs = xv[i];
      const float* wrow = rw + (long)(h0 + i) * NEXP;
      #pragma unroll
      for (int e = 0; e < 16; e++) acc[e] += xs * wrow[e];
      acc[16] += xs * sgw[h0 + i];
    }
  }
  #pragma unroll
  for (int e = 0; e < 17; e++)
    for (int off = 32; off >= 1; off >>= 1)
      acc[e] += __shfl_xor(acc[e], off);
  if (lane == 0){
    float* lo = logits + (long)t * NEXP;
    #pragma unroll
    for (int e = 0; e < 16; e++) lo[e] = acc[e];
    int e0 = 0;
    #pragma unroll
    for (int e = 1; e < 16; e++) if (acc[e] > acc[e0]) e0 = e;
    int e1 = (e0 == 0) ? 1 : 0;
    #pragma unroll
    for (int e = 0; e < 16; e++) if (e != e0 && acc[e] > acc[e1]) e1 = e;
    float d = acc[e1] - acc[e0];
    float ed = __expf(d);
    float p0 = 1.f / (1.f + ed);
    float p1 = ed / (1.f + ed);
    int pos0 = atomicAdd(&counts[e0], 1);
    lists[e0 * T_TOK + pos0] = t; probs[e0 * T_TOK + pos0] = p0;
    int pos1 = atomicAdd(&counts[e1], 1);
    lists[e1 * T_TOK + pos1] = t; probs[e1 * T_TOK + pos1] = p1;
    sgmul[t] = 1.f / (1.f + __expf(-acc[16]));
  }
}

// ---------------- padded prefix bases (128-aligned) ----------------
__global__ void bases_k(const int* __restrict__ counts, int* __restrict__ bases){
  if (threadIdx.x == 0){
    int r = 0;
    for (int e = 0; e < NEXP; e++){ bases[e] = r; r += (counts[e] + 127) & ~127; }
  }
}

// ---------------- SwiGLU elementwise ----------------
__global__ void swiglu_expert_k(const ushort_t* __restrict__ gu, ushort_t* __restrict__ hid){
  long qd = (long)blockIdx.x * 256 + threadIdx.x;
  long r = qd / (I_DIM / 8); int ic = (int)(qd % (I_DIM / 8)) * 8;
  const ushort_t* g = gu + r * I2_DIM + ic;
  u16x8 gv = *(const u16x8*)g;
  u16x8 uv = *(const u16x8*)(g + I_DIM);
  u16x8 ov;
  #pragma unroll
  for (int i = 0; i < 8; i++)
    ov[i] = f2bf(bf2f(uv[i]) * silu_f(bf2f(gv[i])));
  *(u16x8*)&hid[r * I_DIM + ic] = ov;
}

__global__ void swiglu_flat_k(ushort_t* __restrict__ sg, const ushort_t* __restrict__ si){
  long i = ((long)blockIdx.x * 256 + threadIdx.x) * 8;
  u16x8 g = *(const u16x8*)&sg[i];
  u16x8 s = *(const u16x8*)&si[i];
  u16x8 o;
  #pragma unroll
  for (int j = 0; j < 8; j++)
    o[j] = f2bf(bf2f(s[j]) * silu_f(bf2f(g[j])));
  *(u16x8*)&sg[i] = o;
}

// ======== GEMM core: 128x128 / BK=32 / 4 waves, 2-buffer counted pipeline ========
// 32 KiB LDS -> 5 blocks/CU (20 waves/CU): cross-block TLP hides the per-wave drain (m114).
// Per iter: vmcnt(0) [drains stage issued one compute-phase ago] -> s_barrier ->
// stage(t+1 -> other buf) -> 8 asm ds_read (cur buf) -> lgkmcnt(0) -> 16 MFMA (setprio).
static __device__ __forceinline__ void gemm_core(
    const ushort_t* __restrict__ Ab, int lda,
    const ushort_t* __restrict__ Bb, int ldbt,
    int kb, int m0, int n0, int cnt,
    const int* __restrict__ gather,      // null = dense A rows
    int emode, ushort_t* __restrict__ Cb, int ldc, long rbase,
    const int* __restrict__ sclist, const float* __restrict__ scprob,
    const float* __restrict__ svec, float* __restrict__ outp){
  __shared__ ushort_t lds[2 * 8192];     // 2 bufs x (A 4096 + B 4096) elems = 32 KiB
  unsigned lbase = (unsigned)(size_t)(__attribute__((address_space(3))) ushort_t*)lds;

  int tid = threadIdx.x;
  int lane = tid & 63;
  int wv = tid >> 6;        // 4 waves
  int wm = wv >> 1;
  int wn = wv & 1;

  int srow = lane >> 2;
  int sslot = ((lane & 3) ^ (srow & 3)) * 8;
  long aoff[2], boff[2];
  #pragma unroll
  for (int c = 0; c < 2; c++){
    int mr = wv * 32 + c * 16 + srow;
    int grow;
    if (gather){
      int j = m0 + mr; if (j >= cnt) j = cnt - 1;
      grow = gather[j];
    } else {
      grow = m0 + mr;
    }
    aoff[c] = (long)grow * lda + sslot;
    boff[c] = (long)(n0 + mr) * ldbt + sslot;
  }

  auto stage = [&](int t, int buf){
    long ko = (long)t * 32;
    ushort_t* dA = lds + buf * 8192 + wv * 1024;
    ushort_t* dB = dA + 4096;
    gld16(Ab + aoff[0] + ko, dA);
    gld16(Ab + aoff[1] + ko, dA + 512);
    gld16(Bb + boff[0] + ko, dB);
    gld16(Bb + boff[1] + ko, dB + 512);
  };

  f32x4 zero = {0.f, 0.f, 0.f, 0.f};
  f32x4 acc[4][4];
  #pragma unroll
  for (int i = 0; i < 4; i++)
    #pragma unroll
    for (int j = 0; j < 4; j++) acc[i][j] = zero;

  int fr = lane & 15;
  int kg = lane >> 4;
  unsigned ps = (unsigned)((kg ^ (fr & 3)) << 4);
  unsigned aoffb = (unsigned)((wm * 64 + fr) * 64) + ps;
  unsigned boffb = 8192u + (unsigned)((wn * 64 + fr) * 64) + ps;

  int nt = kb >> 5;
  stage(0, 0);

  for (int t = 0; t < nt; t++){
    asm volatile("s_waitcnt vmcnt(0)" ::: "memory");
    __builtin_amdgcn_s_barrier();
    __builtin_amdgcn_sched_barrier(0);
    if (t + 1 < nt) stage(t + 1, (t + 1) & 1);
    __builtin_amdgcn_sched_barrier(0);
    unsigned bufb = lbase + (unsigned)(t & 1) * 16384u;
    bf16x8 af[4], bg[4];
    #pragma unroll
    for (int f = 0; f < 4; f++){
      af[f] = dsr128(bufb + aoffb + f * 1024u);
      bg[f] = dsr128(bufb + boffb + f * 1024u);
    }
    asm volatile("s_waitcnt lgkmcnt(0)" ::: "memory");
    __builtin_amdgcn_sched_barrier(0);
    __builtin_amdgcn_s_setprio(1);
    #pragma unroll
    for (int fm = 0; fm < 4; fm++)
      #pragma unroll
      for (int fn = 0; fn < 4; fn++)
        acc[fm][fn] = __builtin_amdgcn_mfma_f32_16x16x32_bf16(af[fm], bg[fn], acc[fm][fn], 0, 0, 0);
    __builtin_amdgcn_s_setprio(0);
  }

  int colb = n0 + wn * 64 + (lane & 15);
  int rowb = m0 + wm * 64 + (lane >> 4) * 4;
  #pragma unroll
  for (int fm = 0; fm < 4; fm++){
    #pragma unroll
    for (int fn = 0; fn < 4; fn++){
      f32x4 v = acc[fm][fn];
      int col = colb + fn * 16;
      #pragma unroll
      for (int rr = 0; rr < 4; rr++){
        int m = rowb + fm * 16 + rr;
        if (emode == 0){
          Cb[(long)m * ldc + col] = f2bf(v[rr]);
        } else if (emode == 1){
          if (m < cnt) Cb[(rbase + m) * (long)ldc + col] = f2bf(v[rr]);
        } else if (emode == 2){
          if (m < cnt){
            int tok = sclist[m];
            atomicAdd(outp + (long)tok * ldc + col, scprob[m] * v[rr]);
          }
        } else {
          atomicAdd(outp + (long)m * ldc + col, svec[m] * v[rr]);
        }
      }
    }
  }
}

// bijective XCD-chunked swizzle (m204), m-fastest decode.
static __device__ __forceinline__ int swz_wg(){
  int nwg = gridDim.x;
  int wgo = blockIdx.x;
  int q = nwg >> 3, r = nwg & 7;
  int xcd = wgo & 7, idx = wgo >> 3;
  return (xcd < r ? xcd * (q + 1) : r * (q + 1) + (xcd - r) * q) + idx;
}

// ---- merged "up" GEMMs: z<2 shared gate/inter (dense, store slab); z>=2 expert gate_up ----
__global__ __launch_bounds__(256) void g_up(
    const ushort_t* xb, const ushort_t* wsg_t, const ushort_t* wsi_t,
    const ushort_t* wgu_t, ushort_t* sgr, ushort_t* gu,
    const int* counts, const int* bases, const int* lists){
  int z = blockIdx.z;
  int wg = swz_wg();
  int mblk = wg & 15, nblk = wg >> 4;     // gridDim.x = 704 = 16 m x 44 n
  int m0 = mblk * 128, n0 = nblk * 128;
  if (z < 2){
    gemm_core(xb, H_DIM, (z ? wsi_t : wsg_t), H_DIM, H_DIM, m0, n0, T_TOK,
              nullptr, 0, sgr + (size_t)z * T_TOK * IS_DIM, IS_DIM, 0,
              nullptr, nullptr, nullptr, nullptr);
  } else {
    int e = z - 2;
    if (nblk >= I2_DIM / 128) return;
    int cnt = counts[e];
    if (m0 >= cnt) return;
    gemm_core(xb, H_DIM, wgu_t + (size_t)e * I2_DIM * H_DIM, H_DIM, H_DIM,
              m0, n0, cnt, lists + e * T_TOK,
              1, gu, I2_DIM, bases[e],
              nullptr, nullptr, nullptr, nullptr);
  }
}

// ---- merged "down" GEMMs: z<4 shared out (K-split quarters, svec); z>=4 expert out ----
__global__ __launch_bounds__(256) void g_down(
    const ushort_t* sgr, const ushort_t* hid,
    const ushort_t* wso_t, const ushort_t* wout_t,
    const int* counts, const int* bases, const int* lists,
    const float* probs, const float* sgmul, float* out){
  int z = blockIdx.z;
  int wg = swz_wg();
  int mblk = wg & 15, nblk = wg >> 4;     // gridDim.x = 256 = 16 m x 16 n
  int m0 = mblk * 128, n0 = nblk * 128;
  if (z < 4){
    // K-split: quarter z of K=IS_DIM
    gemm_core(sgr + z * (IS_DIM / 4), IS_DIM, wso_t + z * (IS_DIM / 4), IS_DIM,
              IS_DIM / 4, m0, n0, T_TOK, nullptr,
              3, nullptr, H_DIM, 0,
              nullptr, nullptr, sgmul, out);
  } else {
    int e = z - 4;
    int cnt = counts[e];
    if (m0 >= cnt) return;
    gemm_core(hid + (size_t)bases[e] * I_DIM, I_DIM,
              wout_t + (size_t)e * H_DIM * I_DIM, I_DIM,
              I_DIM, m0, n0, cnt, nullptr,
              2, nullptr, H_DIM, 0,
              lists + e * T_TOK, probs + e * T_TOK, nullptr, out);
  }
}

extern "C" void kernel_launch(void* const* d_in, const int* in_sizes, int n_in,
                              void* d_out, int out_size, void* d_ws, size_t ws_size,
                              hipStream_t stream){
  const float* x    = (const float*)d_in[0];
  const float* rw   = (const float*)d_in[1];
  const float* wgu  = (const float*)d_in[2];
  const float* wout = (const float*)d_in[3];
  const float* wsg  = (const float*)d_in[4];
  const float* wsi  = (const float*)d_in[5];
  const float* wso  = (const float*)d_in[6];
  const float* sgw  = (const float*)d_in[7];

  float* out = (float*)d_out;
  float* logits = out + (size_t)T_TOK * H_DIM;

  char* w = (char*)d_ws;
  auto alloc = [&](size_t b){ char* p = w; w += (b + 255) & ~(size_t)255; return p; };
  ushort_t* xb     = (ushort_t*)alloc((size_t)T_TOK * H_DIM * 2);
  ushort_t* wgu_t  = (ushort_t*)alloc((size_t)NEXP * I2_DIM * H_DIM * 2);
  ushort_t* wout_t = (ushort_t*)alloc((size_t)NEXP * H_DIM * I_DIM * 2);
  ushort_t* wsg_t  = (ushort_t*)alloc((size_t)IS_DIM * H_DIM * 2);
  ushort_t* wsi_t  = (ushort_t*)alloc((size_t)IS_DIM * H_DIM * 2);
  ushort_t* wso_t  = (ushort_t*)alloc((size_t)H_DIM * IS_DIM * 2);
  ushort_t* sgr    = (ushort_t*)alloc((size_t)2 * T_TOK * IS_DIM * 2);
  ushort_t* sir    = sgr + (size_t)T_TOK * IS_DIM;
  ushort_t* gu     = (ushort_t*)alloc((size_t)MAXROWS * I2_DIM * 2);
  ushort_t* hid    = (ushort_t*)alloc((size_t)MAXROWS * I_DIM * 2);
  int*   counts = (int*)alloc(64);
  int*   bases  = (int*)alloc(64);
  int*   lists  = (int*)alloc((size_t)NEXP * T_TOK * 4);
  float* probs  = (float*)alloc((size_t)NEXP * T_TOK * 4);
  float* sgmul  = (float*)alloc((size_t)T_TOK * 4);

  hipMemsetAsync(counts, 0, 64, stream);
  hipMemsetAsync(out, 0, (size_t)T_TOK * H_DIM * sizeof(float), stream);

  cast_bf16_k<<<2048, 256, 0, stream>>>(x, xb);
  transpose_cast_k<<<dim3(I2_DIM/64, H_DIM/64, NEXP), 256, 0, stream>>>(wgu, wgu_t, H_DIM, I2_DIM);
  transpose_cast_k<<<dim3(H_DIM/64, I_DIM/64, NEXP), 256, 0, stream>>>(wout, wout_t, I_DIM, H_DIM);
  transpose_cast_k<<<dim3(IS_DIM/64, H_DIM/64, 1), 256, 0, stream>>>(wsg, wsg_t, H_DIM, IS_DIM);
  transpose_cast_k<<<dim3(IS_DIM/64, H_DIM/64, 1), 256, 0, stream>>>(wsi, wsi_t, H_DIM, IS_DIM);
  transpose_cast_k<<<dim3(H_DIM/64, IS_DIM/64, 1), 256, 0, stream>>>(wso, wso_t, IS_DIM, H_DIM);

  router_k<<<512, 256, 0, stream>>>(x, rw, sgw, logits, counts, lists, probs, sgmul);
  bases_k<<<1, 64, 0, stream>>>(counts, bases);

  // merged up-projections: shared gate+inter (z 0,1) + 16 expert gate_up (z 2..17)
  g_up<<<dim3(16 * (IS_DIM/128), 1, 2 + NEXP), 256, 0, stream>>>(
      xb, wsg_t, wsi_t, wgu_t, sgr, gu, counts, bases, lists);

  swiglu_flat_k<<<(T_TOK * (IS_DIM/8)) / 256, 256, 0, stream>>>(sgr, sir);
  swiglu_expert_k<<<((long)MAXROWS * (I_DIM/8)) / 256, 256, 0, stream>>>(gu, hid);

  // merged down-projections: shared out K-split x4 (z 0..3) + 16 expert out (z 4..19)
  g_down<<<dim3(16 * (H_DIM/128), 1, 4 + NEXP), 256, 0, stream>>>(
      sgr, hid, wso_t, wout_t, counts, bases, lists, probs, sgmul, out);

  (void)in_sizes; (void)n_in; (void)out_size; (void)ws_size;
}

// Round 13
// 779.296 us; speedup vs baseline: 1.1068x; 1.1068x over previous
//
#include <hip/hip_runtime.h>
#include <math.h>

typedef __attribute__((ext_vector_type(4))) float f32x4;
typedef __attribute__((ext_vector_type(2))) unsigned int u32x2;
typedef __attribute__((ext_vector_type(4))) unsigned int u32x4;
typedef __attribute__((ext_vector_type(8))) unsigned short u16x8;
typedef __attribute__((ext_vector_type(8))) __bf16 bf16x8;
typedef unsigned short ushort_t;

#define H_DIM 2048
#define T_TOK 2048
#define NEXP 16
#define I_DIM 1408
#define I2_DIM 2816
#define IS_DIM 5632
#define MAXROWS 6144

static __device__ __forceinline__ unsigned short f2bf(float f){
  union { float f; unsigned u; } v; v.f = f;
  unsigned r = v.u + 0x7FFFu + ((v.u >> 16) & 1u);
  return (unsigned short)(r >> 16);
}
static __device__ __forceinline__ float bf2f(unsigned short h){
  union { unsigned u; float f; } v; v.u = ((unsigned)h) << 16;
  return v.f;
}
static __device__ __forceinline__ float silu_f(float x){ return x / (1.f + __expf(-x)); }

// async global->LDS, 16B/lane; LDS dest wave-uniform base, HW adds lane*16.
static __device__ __forceinline__ void gld16(const ushort_t* g, ushort_t* l){
  __builtin_amdgcn_global_load_lds(
      (const __attribute__((address_space(1))) unsigned int*)g,
      (__attribute__((address_space(3))) unsigned int*)l, 16, 0, 0);
}

// inline-asm ds_read_b128: opaque to LDS-DMA alias tracking (no forced vmcnt drain).
static __device__ __forceinline__ bf16x8 dsr128(unsigned byte_off){
  u32x4 r;
  asm volatile("ds_read_b128 %0, %1" : "=v"(r) : "v"(byte_off));
  return __builtin_bit_cast(bf16x8, r);
}

// ---------------- merged transpose+cast: all 5 weight tensors in one launch ----------------
// body: one 64x64 tile of in[K][N] fp32 -> out[N][K] bf16
static __device__ __forceinline__ void tr_tile(const float* __restrict__ in,
                                               ushort_t* __restrict__ out,
                                               int K, int N, int k0, int n0){
  __shared__ float tl[64][65];
  int tid = threadIdx.x;           // 256
  int lr = tid >> 2;
  int lv = (tid & 3) * 4;
  #pragma unroll
  for (int j = 0; j < 4; j++){
    int col = lv + j * 16;
    f32x4 v = *(const f32x4*)&in[(long)(k0 + lr) * N + n0 + col];
    tl[lr][col + 0] = v[0]; tl[lr][col + 1] = v[1];
    tl[lr][col + 2] = v[2]; tl[lr][col + 3] = v[3];
  }
  __syncthreads();
  int nl = tid >> 3;
  int kc = (tid & 7) * 8;
  #pragma unroll
  for (int it = 0; it < 2; it++){
    int n = nl + it * 32;
    union { ushort_t s[8]; u32x4 v; } pk;
    #pragma unroll
    for (int j = 0; j < 8; j++) pk.s[j] = f2bf(tl[kc + j][n]);
    *(u32x4*)&out[(long)(n0 + n) * K + k0 + kc] = pk.v;
  }
}

// segments (exact block counts, no waste):
// s0 wgu  [16][2048][2816]: 16 * 44nx * 32ky = 22528
// s1 wout [16][1408][2048]: 16 * 32nx * 22ky = 11264
// s2 wsg  [2048][5632]:     88nx * 32ky      =  2816
// s3 wsi  [2048][5632]:                         2816
// s4 wso  [5632][2048]:     32nx * 88ky      =  2816
#define TR_O1 22528
#define TR_O2 33792
#define TR_O3 36608
#define TR_O4 39424
#define TR_TOT 42240

__global__ void transpose_all_k(const float* __restrict__ wgu, const float* __restrict__ wout,
                                const float* __restrict__ wsg, const float* __restrict__ wsi,
                                const float* __restrict__ wso,
                                ushort_t* __restrict__ wgu_t, ushort_t* __restrict__ wout_t,
                                ushort_t* __restrict__ wsg_t, ushort_t* __restrict__ wsi_t,
                                ushort_t* __restrict__ wso_t){
  int b = blockIdx.x;
  if (b < TR_O1){
    int e = b / (44 * 32), r = b % (44 * 32);
    int nx = r % 44, ky = r / 44;
    long zo = (long)e * H_DIM * I2_DIM;
    tr_tile(wgu + zo, wgu_t + zo, H_DIM, I2_DIM, ky * 64, nx * 64);
  } else if (b < TR_O2){
    int r = b - TR_O1;
    int e = r / (32 * 22); r %= (32 * 22);
    int nx = r % 32, ky = r / 32;
    long zo = (long)e * I_DIM * H_DIM;
    tr_tile(wout + zo, wout_t + zo, I_DIM, H_DIM, ky * 64, nx * 64);
  } else if (b < TR_O3){
    int r = b - TR_O2;
    int nx = r % 88, ky = r / 88;
    tr_tile(wsg, wsg_t, H_DIM, IS_DIM, ky * 64, nx * 64);
  } else if (b < TR_O4){
    int r = b - TR_O3;
    int nx = r % 88, ky = r / 88;
    tr_tile(wsi, wsi_t, H_DIM, IS_DIM, ky * 64, nx * 64);
  } else {
    int r = b - TR_O4;
    int nx = r % 32, ky = r / 32;
    tr_tile(wso, wso_t, IS_DIM, H_DIM, ky * 64, nx * 64);
  }
}

// ---------------- router (+ fused x->bf16 cast) ----------------
__global__ void router_k(const float* __restrict__ x, const float* __restrict__ rw,
                         const float* __restrict__ sgw, float* __restrict__ logits,
                         int* __restrict__ counts, int* __restrict__ lists,
                         float* __restrict__ probs, float* __restrict__ sgmul,
                         ushort_t* __restrict__ xb){
  int wid = threadIdx.x >> 6, lane = threadIdx.x & 63;
  int t = blockIdx.x * 4 + wid;
  const float* xr = x + (long)t * H_DIM;
  ushort_t* xbr = xb + (long)t * H_DIM;
  float acc[17];
  #pragma unroll
  for (int e = 0; e < 17; e++) acc[e] = 0.f;
  for (int h0 = lane * 4; h0 < H_DIM; h0 += 256){
    f32x4 xv = *(const f32x4*)&xr[h0];
    // fused cast: write these 4 elements as bf16 (coalesced 8B/lane)
    u32x2 pk;
    pk[0] = (unsigned)f2bf(xv[0]) | ((unsigned)f2bf(xv[1]) << 16);
    pk[1] = (unsigned)f2bf(xv[2]) | ((unsigned)f2bf(xv[3]) << 16);
    *(u32x2*)&xbr[h0] = pk;
    #pragma unroll
    for (int i = 0; i < 4; i++){
      float xs = xv[i];
      const float* wrow = rw + (long)(h0 + i) * NEXP;
      #pragma unroll
      for (int e = 0; e < 16; e++) acc[e] += xs * wrow[e];
      acc[16] += xs * sgw[h0 + i];
    }
  }
  #pragma unroll
  for (int e = 0; e < 17; e++)
    for (int off = 32; off >= 1; off >>= 1)
      acc[e] += __shfl_xor(acc[e], off);
  if (lane == 0){
    float* lo = logits + (long)t * NEXP;
    #pragma unroll
    for (int e = 0; e < 16; e++) lo[e] = acc[e];
    int e0 = 0;
    #pragma unroll
    for (int e = 1; e < 16; e++) if (acc[e] > acc[e0]) e0 = e;
    int e1 = (e0 == 0) ? 1 : 0;
    #pragma unroll
    for (int e = 0; e < 16; e++) if (e != e0 && acc[e] > acc[e1]) e1 = e;
    float d = acc[e1] - acc[e0];
    float ed = __expf(d);
    float p0 = 1.f / (1.f + ed);
    float p1 = ed / (1.f + ed);
    int pos0 = atomicAdd(&counts[e0], 1);
    lists[e0 * T_TOK + pos0] = t; probs[e0 * T_TOK + pos0] = p0;
    int pos1 = atomicAdd(&counts[e1], 1);
    lists[e1 * T_TOK + pos1] = t; probs[e1 * T_TOK + pos1] = p1;
    sgmul[t] = 1.f / (1.f + __expf(-acc[16]));
  }
}

// ---------------- padded prefix bases (128-aligned) ----------------
__global__ void bases_k(const int* __restrict__ counts, int* __restrict__ bases){
  if (threadIdx.x == 0){
    int r = 0;
    for (int e = 0; e < NEXP; e++){ bases[e] = r; r += (counts[e] + 127) & ~127; }
  }
}

// ---------------- SwiGLU elementwise ----------------
__global__ void swiglu_expert_k(const ushort_t* __restrict__ gu, ushort_t* __restrict__ hid){
  long qd = (long)blockIdx.x * 256 + threadIdx.x;
  long r = qd / (I_DIM / 8); int ic = (int)(qd % (I_DIM / 8)) * 8;
  const ushort_t* g = gu + r * I2_DIM + ic;
  u16x8 gv = *(const u16x8*)g;
  u16x8 uv = *(const u16x8*)(g + I_DIM);
  u16x8 ov;
  #pragma unroll
  for (int i = 0; i < 8; i++)
    ov[i] = f2bf(bf2f(uv[i]) * silu_f(bf2f(gv[i])));
  *(u16x8*)&hid[r * I_DIM + ic] = ov;
}

__global__ void swiglu_flat_k(ushort_t* __restrict__ sg, const ushort_t* __restrict__ si){
  long i = ((long)blockIdx.x * 256 + threadIdx.x) * 8;
  u16x8 g = *(const u16x8*)&sg[i];
  u16x8 s = *(const u16x8*)&si[i];
  u16x8 o;
  #pragma unroll
  for (int j = 0; j < 8; j++)
    o[j] = f2bf(bf2f(s[j]) * silu_f(bf2f(g[j])));
  *(u16x8*)&sg[i] = o;
}

// ======== R8 GEMM core: 128x128 / BK=32 / 4 waves, 3-buffer counted-vmcnt, asm ds_read ========
// (setprio removed per m190: null-to-negative on non-phase-split GEMM structures)
template<int MODE>
static __device__ __forceinline__ void gemm3_body(
    const ushort_t* __restrict__ A, const ushort_t* __restrict__ Bt,
    const ushort_t* __restrict__ Bt2, ushort_t* __restrict__ Cb,
    int K, int lda, int ldbt, int ldc, int mb,
    const int* __restrict__ counts, const int* __restrict__ bases,
    const int* __restrict__ lists, const float* __restrict__ probs,
    const float* __restrict__ svec, float* __restrict__ outp, long bstride){
  int z = blockIdx.z;
  int cnt = T_TOK;
  const ushort_t* Ab = A;
  const ushort_t* Bb = Bt;
  long rbase = 0;
  if constexpr (MODE == 0){ if (z){ Bb = Bt2; Cb += (long)T_TOK * ldc; } }
  if constexpr (MODE == 1){ cnt = counts[z]; rbase = bases[z]; Bb += (long)z * bstride; }
  if constexpr (MODE == 2){ cnt = counts[z]; Ab += (long)bases[z] * lda; Bb += (long)z * bstride; }

  int kb = K / gridDim.y;          // MODE 3 K-split; others gridDim.y==1
  int kbase = blockIdx.y * kb;
  Ab += kbase;
  Bb += kbase;                     // Bt is [N][K], k fastest

  // bijective XCD-chunked swizzle (m204)
  int nwg = gridDim.x;
  int wgo = blockIdx.x;
  int q = nwg >> 3, r = nwg & 7;
  int xcd = wgo & 7, idx = wgo >> 3;
  int wg = (xcd < r ? xcd * (q + 1) : r * (q + 1) + (xcd - r) * q) + idx;
  int m0 = (wg % mb) * 128;
  if (m0 >= cnt) return;
  int n0 = (wg / mb) * 128;

  __shared__ ushort_t lds[3 * 8192];     // 3 bufs x (A 4096 + B 4096) elems = 48 KiB
  unsigned lbase = (unsigned)(size_t)(__attribute__((address_space(3))) ushort_t*)lds;

  int tid = threadIdx.x;
  int lane = tid & 63;
  int wv = tid >> 6;        // 4 waves
  int wm = wv >> 1;
  int wn = wv & 1;

  int srow = lane >> 2;
  int sslot = ((lane & 3) ^ (srow & 3)) * 8;
  long aoff[2], boff[2];
  #pragma unroll
  for (int c = 0; c < 2; c++){
    int mr = wv * 32 + c * 16 + srow;
    int grow;
    if constexpr (MODE == 1){
      int j = m0 + mr; if (j >= cnt) j = cnt - 1;
      grow = lists[z * T_TOK + j];
    } else {
      grow = m0 + mr;
    }
    aoff[c] = (long)grow * lda + sslot;
    boff[c] = (long)(n0 + mr) * ldbt + sslot;
  }

  auto stage = [&](int t, int buf){
    long ko = (long)t * 32;
    ushort_t* dA = lds + buf * 8192 + wv * 1024;
    ushort_t* dB = dA + 4096;
    gld16(Ab + aoff[0] + ko, dA);
    gld16(Ab + aoff[1] + ko, dA + 512);
    gld16(Bb + boff[0] + ko, dB);
    gld16(Bb + boff[1] + ko, dB + 512);
  };

  f32x4 zero = {0.f, 0.f, 0.f, 0.f};
  f32x4 acc[4][4];
  #pragma unroll
  for (int i = 0; i < 4; i++)
    #pragma unroll
    for (int j = 0; j < 4; j++) acc[i][j] = zero;

  int fr = lane & 15;
  int kg = lane >> 4;
  unsigned ps = (unsigned)((kg ^ (fr & 3)) << 4);
  unsigned aoffb = (unsigned)((wm * 64 + fr) * 64) + ps;
  unsigned boffb = 8192u + (unsigned)((wn * 64 + fr) * 64) + ps;

  int nt = kb >> 5;
  stage(0, 0);
  __builtin_amdgcn_sched_barrier(0);
  stage(1, 1);

  int rb = 0, sb = 2;
  for (int t = 0; t < nt; t++){
    if (t + 2 < nt) asm volatile("s_waitcnt vmcnt(4)" ::: "memory");
    else            asm volatile("s_waitcnt vmcnt(0)" ::: "memory");
    __builtin_amdgcn_s_barrier();
    __builtin_amdgcn_sched_barrier(0);
    unsigned bufb = lbase + (unsigned)rb * 16384u;
    bf16x8 af[4], bg[4];
    #pragma unroll
    for (int f = 0; f < 4; f++){
      af[f] = dsr128(bufb + aoffb + f * 1024u);
      bg[f] = dsr128(bufb + boffb + f * 1024u);
    }
    __builtin_amdgcn_sched_barrier(0);
    if (t + 2 < nt) stage(t + 2, sb);
    asm volatile("s_waitcnt lgkmcnt(0)" ::: "memory");
    __builtin_amdgcn_sched_barrier(0);
    #pragma unroll
    for (int fm = 0; fm < 4; fm++)
      #pragma unroll
      for (int fn = 0; fn < 4; fn++)
        acc[fm][fn] = __builtin_amdgcn_mfma_f32_16x16x32_bf16(af[fm], bg[fn], acc[fm][fn], 0, 0, 0);
    rb = (rb == 2) ? 0 : rb + 1;
    sb = (sb == 2) ? 0 : sb + 1;
  }

  int colb = n0 + wn * 64 + (lane & 15);
  int rowb = m0 + wm * 64 + (lane >> 4) * 4;
  #pragma unroll
  for (int fm = 0; fm < 4; fm++){
    #pragma unroll
    for (int fn = 0; fn < 4; fn++){
      f32x4 v = acc[fm][fn];
      int col = colb + fn * 16;
      #pragma unroll
      for (int rr = 0; rr < 4; rr++){
        int m = rowb + fm * 16 + rr;
        if constexpr (MODE == 0){
          Cb[(long)m * ldc + col] = f2bf(v[rr]);
        } else if constexpr (MODE == 1){
          if (m < cnt) Cb[(rbase + m) * (long)ldc + col] = f2bf(v[rr]);
        } else if constexpr (MODE == 2){
          if (m < cnt){
            int tok = lists[z * T_TOK + m];
            float pp = probs[z * T_TOK + m];
            atomicAdd(outp + (long)tok * ldc + col, pp * v[rr]);
          }
        } else {
          atomicAdd(outp + (long)m * ldc + col, svec[m] * v[rr]);
        }
      }
    }
  }
}

// distinct names so rocprof top-k localizes cost per mode
#define GEMM_ARGS const ushort_t* A, const ushort_t* Bt, const ushort_t* Bt2, ushort_t* Cb, \
    int K, int lda, int ldbt, int ldc, int mb, const int* counts, const int* bases, \
    const int* lists, const float* probs, const float* svec, float* outp, long bstride
#define GEMM_PASS A, Bt, Bt2, Cb, K, lda, ldbt, ldc, mb, counts, bases, lists, probs, svec, outp, bstride

__global__ __launch_bounds__(256) void g_shared_gi(GEMM_ARGS){ gemm3_body<0>(GEMM_PASS); }
__global__ __launch_bounds__(256) void g_shared_out(GEMM_ARGS){ gemm3_body<3>(GEMM_PASS); }
__global__ __launch_bounds__(256) void g_expert_gu(GEMM_ARGS){ gemm3_body<1>(GEMM_PASS); }
__global__ __launch_bounds__(256) void g_expert_out(GEMM_ARGS){ gemm3_body<2>(GEMM_PASS); }

extern "C" void kernel_launch(void* const* d_in, const int* in_sizes, int n_in,
                              void* d_out, int out_size, void* d_ws, size_t ws_size,
                              hipStream_t stream){
  const float* x    = (const float*)d_in[0];
  const float* rw   = (const float*)d_in[1];
  const float* wgu  = (const float*)d_in[2];
  const float* wout = (const float*)d_in[3];
  const float* wsg  = (const float*)d_in[4];
  const float* wsi  = (const float*)d_in[5];
  const float* wso  = (const float*)d_in[6];
  const float* sgw  = (const float*)d_in[7];

  float* out = (float*)d_out;
  float* logits = out + (size_t)T_TOK * H_DIM;

  char* w = (char*)d_ws;
  auto alloc = [&](size_t b){ char* p = w; w += (b + 255) & ~(size_t)255; return p; };
  ushort_t* xb     = (ushort_t*)alloc((size_t)T_TOK * H_DIM * 2);
  ushort_t* wgu_t  = (ushort_t*)alloc((size_t)NEXP * I2_DIM * H_DIM * 2);
  ushort_t* wout_t = (ushort_t*)alloc((size_t)NEXP * H_DIM * I_DIM * 2);
  ushort_t* wsg_t  = (ushort_t*)alloc((size_t)IS_DIM * H_DIM * 2);
  ushort_t* wsi_t  = (ushort_t*)alloc((size_t)IS_DIM * H_DIM * 2);
  ushort_t* wso_t  = (ushort_t*)alloc((size_t)H_DIM * IS_DIM * 2);
  ushort_t* sgr    = (ushort_t*)alloc((size_t)2 * T_TOK * IS_DIM * 2);
  ushort_t* sir    = sgr + (size_t)T_TOK * IS_DIM;
  ushort_t* gu     = (ushort_t*)alloc((size_t)MAXROWS * I2_DIM * 2);
  ushort_t* hid    = (ushort_t*)alloc((size_t)MAXROWS * I_DIM * 2);
  int*   counts = (int*)alloc(64);
  int*   bases  = (int*)alloc(64);
  int*   lists  = (int*)alloc((size_t)NEXP * T_TOK * 4);
  float* probs  = (float*)alloc((size_t)NEXP * T_TOK * 4);
  float* sgmul  = (float*)alloc((size_t)T_TOK * 4);

  hipMemsetAsync(counts, 0, 64, stream);
  hipMemsetAsync(out, 0, (size_t)T_TOK * H_DIM * sizeof(float), stream);

  transpose_all_k<<<TR_TOT, 256, 0, stream>>>(wgu, wout, wsg, wsi, wso,
                                              wgu_t, wout_t, wsg_t, wsi_t, wso_t);
  router_k<<<512, 256, 0, stream>>>(x, rw, sgw, logits, counts, lists, probs, sgmul, xb);
  bases_k<<<1, 64, 0, stream>>>(counts, bases);

  // shared expert: gate & inter in one launch (z selects weight)
  g_shared_gi<<<dim3((T_TOK/128) * (IS_DIM/128), 1, 2), 256, 0, stream>>>(
      xb, wsg_t, wsi_t, sgr, H_DIM, H_DIM, H_DIM, IS_DIM, T_TOK/128,
      nullptr, nullptr, nullptr, nullptr, nullptr, nullptr, 0);
  swiglu_flat_k<<<(T_TOK * (IS_DIM/8)) / 256, 256, 0, stream>>>(sgr, sir);
  // shared out-projection, K-split x4, atomic accumulate into zeroed out
  g_shared_out<<<dim3((T_TOK/128) * (H_DIM/128), 4, 1), 256, 0, stream>>>(
      sgr, wso_t, nullptr, nullptr, IS_DIM, IS_DIM, IS_DIM, H_DIM, T_TOK/128,
      nullptr, nullptr, nullptr, nullptr, sgmul, out, 0);

  // sparse routed experts (atomic add on top of shared output)
  g_expert_gu<<<dim3((T_TOK/128) * (I2_DIM/128), 1, NEXP), 256, 0, stream>>>(
      xb, wgu_t, nullptr, gu, H_DIM, H_DIM, H_DIM, I2_DIM, T_TOK/128,
      counts, bases, lists, probs, nullptr, nullptr, (long)I2_DIM * H_DIM);
  swiglu_expert_k<<<((long)MAXROWS * (I_DIM/8)) / 256, 256, 0, stream>>>(gu, hid);
  g_expert_out<<<dim3((T_TOK/128) * (H_DIM/128), 1, NEXP), 256, 0, stream>>>(
      hid, wout_t, nullptr, nullptr, I_DIM, I_DIM, I_DIM, H_DIM, T_TOK/128,
      counts, bases, lists, probs, nullptr, out, (long)I_DIM * H_DIM);

  (void)in_sizes; (void)n_in; (void)out_size; (void)ws_size;
}

// Round 14
// 778.506 us; speedup vs baseline: 1.1080x; 1.0010x over previous
//
#include <hip/hip_runtime.h>
#include <math.h>

typedef __attribute__((ext_vector_type(4))) float f32x4;
typedef __attribute__((ext_vector_type(2))) unsigned int u32x2;
typedef __attribute__((ext_vector_type(4))) unsigned int u32x4;
typedef __attribute__((ext_vector_type(8))) unsigned short u16x8;
typedef __attribute__((ext_vector_type(8))) __bf16 bf16x8;
typedef unsigned short ushort_t;

#define H_DIM 2048
#define T_TOK 2048
#define NEXP 16
#define I_DIM 1408
#define I2_DIM 2816
#define IS_DIM 5632
#define MAXROWS 6144

static __device__ __forceinline__ unsigned short f2bf(float f){
  union { float f; unsigned u; } v; v.f = f;
  unsigned r = v.u + 0x7FFFu + ((v.u >> 16) & 1u);
  return (unsigned short)(r >> 16);
}
static __device__ __forceinline__ float bf2f(unsigned short h){
  union { unsigned u; float f; } v; v.u = ((unsigned)h) << 16;
  return v.f;
}
static __device__ __forceinline__ float silu_f(float x){ return x / (1.f + __expf(-x)); }

// async global->LDS, 16B/lane; LDS dest wave-uniform base, HW adds lane*16.
static __device__ __forceinline__ void gld16(const ushort_t* g, ushort_t* l){
  __builtin_amdgcn_global_load_lds(
      (const __attribute__((address_space(1))) unsigned int*)g,
      (__attribute__((address_space(3))) unsigned int*)l, 16, 0, 0);
}

// inline-asm ds_read_b128: opaque to LDS-DMA alias tracking (no forced vmcnt drain).
static __device__ __forceinline__ bf16x8 dsr128(unsigned byte_off){
  u32x4 r;
  asm volatile("ds_read_b128 %0, %1" : "=v"(r) : "v"(byte_off));
  return __builtin_bit_cast(bf16x8, r);
}

// ---------------- merged transpose+cast v2: 128k x 64n tiles, 256B segments both sides -------
static __device__ __forceinline__ void tr_tile(const float* __restrict__ in,
                                               ushort_t* __restrict__ out,
                                               int K, int N, int k0, int n0){
  __shared__ float tl[128][65];
  int t = threadIdx.x;             // 256
  int lr = t >> 4;                 // 0..15
  int lc = t & 15;                 // 16 lanes cover one 64-float row slice (256B)
  #pragma unroll
  for (int p = 0; p < 8; p++){
    int row = p * 16 + lr;
    f32x4 v = *(const f32x4*)&in[(long)(k0 + row) * N + n0 + lc * 4];
    tl[row][lc*4 + 0] = v[0]; tl[row][lc*4 + 1] = v[1];
    tl[row][lc*4 + 2] = v[2]; tl[row][lc*4 + 3] = v[3];
  }
  __syncthreads();
  #pragma unroll
  for (int p = 0; p < 4; p++){
    int n = p * 16 + lr;
    int kc = lc * 8;               // 16 lanes cover one 128-k out row (256B)
    union { ushort_t s[8]; u32x4 v; } pk;
    #pragma unroll
    for (int j = 0; j < 8; j++) pk.s[j] = f2bf(tl[kc + j][n]);
    *(u32x4*)&out[(long)(n0 + n) * K + k0 + kc] = pk.v;
  }
}

// segments (128k x 64n tiles, exact):
// s0 wgu  [16][2048][2816]: 16 * (16ky * 44nx) = 11264
// s1 wout [16][1408][2048]: 16 * (11ky * 32nx) =  5632
// s2 wsg  [2048][5632]:     16ky * 88nx        =  1408
// s3 wsi  same                                  =  1408
// s4 wso  [5632][2048]:     44ky * 32nx        =  1408
#define TR_O1 11264
#define TR_O2 16896
#define TR_O3 18304
#define TR_O4 19712
#define TR_TOT 21120

__global__ void transpose_all_k(const float* __restrict__ wgu, const float* __restrict__ wout,
                                const float* __restrict__ wsg, const float* __restrict__ wsi,
                                const float* __restrict__ wso,
                                ushort_t* __restrict__ wgu_t, ushort_t* __restrict__ wout_t,
                                ushort_t* __restrict__ wsg_t, ushort_t* __restrict__ wsi_t,
                                ushort_t* __restrict__ wso_t){
  int b = blockIdx.x;
  if (b < TR_O1){
    int e = b / 704, r = b % 704;
    int ky = r / 44, nx = r % 44;
    long zo = (long)e * H_DIM * I2_DIM;
    tr_tile(wgu + zo, wgu_t + zo, H_DIM, I2_DIM, ky * 128, nx * 64);
  } else if (b < TR_O2){
    int r = b - TR_O1;
    int e = r / 352; r %= 352;
    int ky = r / 32, nx = r % 32;
    long zo = (long)e * I_DIM * H_DIM;
    tr_tile(wout + zo, wout_t + zo, I_DIM, H_DIM, ky * 128, nx * 64);
  } else if (b < TR_O3){
    int r = b - TR_O2;
    int ky = r / 88, nx = r % 88;
    tr_tile(wsg, wsg_t, H_DIM, IS_DIM, ky * 128, nx * 64);
  } else if (b < TR_O4){
    int r = b - TR_O3;
    int ky = r / 88, nx = r % 88;
    tr_tile(wsi, wsi_t, H_DIM, IS_DIM, ky * 128, nx * 64);
  } else {
    int r = b - TR_O4;
    int ky = r / 32, nx = r % 32;
    tr_tile(wso, wso_t, IS_DIM, H_DIM, ky * 128, nx * 64);
  }
}

// ---------------- router (+ fused x->bf16 cast) ----------------
__global__ void router_k(const float* __restrict__ x, const float* __restrict__ rw,
                         const float* __restrict__ sgw, float* __restrict__ logits,
                         int* __restrict__ counts, int* __restrict__ lists,
                         float* __restrict__ probs, float* __restrict__ sgmul,
                         ushort_t* __restrict__ xb){
  int wid = threadIdx.x >> 6, lane = threadIdx.x & 63;
  int t = blockIdx.x * 4 + wid;
  const float* xr = x + (long)t * H_DIM;
  ushort_t* xbr = xb + (long)t * H_DIM;
  float acc[17];
  #pragma unroll
  for (int e = 0; e < 17; e++) acc[e] = 0.f;
  for (int h0 = lane * 4; h0 < H_DIM; h0 += 256){
    f32x4 xv = *(const f32x4*)&xr[h0];
    u32x2 pk;
    pk[0] = (unsigned)f2bf(xv[0]) | ((unsigned)f2bf(xv[1]) << 16);
    pk[1] = (unsigned)f2bf(xv[2]) | ((unsigned)f2bf(xv[3]) << 16);
    *(u32x2*)&xbr[h0] = pk;
    #pragma unroll
    for (int i = 0; i < 4; i++){
      float xs = xv[i];
      const float* wrow = rw + (long)(h0 + i) * NEXP;
      #pragma unroll
      for (int e = 0; e < 16; e++) acc[e] += xs * wrow[e];
      acc[16] += xs * sgw[h0 + i];
    }
  }
  #pragma unroll
  for (int e = 0; e < 17; e++)
    for (int off = 32; off >= 1; off >>= 1)
      acc[e] += __shfl_xor(acc[e], off);
  if (lane == 0){
    float* lo = logits + (long)t * NEXP;
    #pragma unroll
    for (int e = 0; e < 16; e++) lo[e] = acc[e];
    int e0 = 0;
    #pragma unroll
    for (int e = 1; e < 16; e++) if (acc[e] > acc[e0]) e0 = e;
    int e1 = (e0 == 0) ? 1 : 0;
    #pragma unroll
    for (int e = 0; e < 16; e++) if (e != e0 && acc[e] > acc[e1]) e1 = e;
    float d = acc[e1] - acc[e0];
    float ed = __expf(d);
    float p0 = 1.f / (1.f + ed);
    float p1 = ed / (1.f + ed);
    int pos0 = atomicAdd(&counts[e0], 1);
    lists[e0 * T_TOK + pos0] = t; probs[e0 * T_TOK + pos0] = p0;
    int pos1 = atomicAdd(&counts[e1], 1);
    lists[e1 * T_TOK + pos1] = t; probs[e1 * T_TOK + pos1] = p1;
    sgmul[t] = 1.f / (1.f + __expf(-acc[16]));
  }
}

// ---------------- padded prefix bases (128-aligned) ----------------
__global__ void bases_k(const int* __restrict__ counts, int* __restrict__ bases){
  if (threadIdx.x == 0){
    int r = 0;
    for (int e = 0; e < NEXP; e++){ bases[e] = r; r += (counts[e] + 127) & ~127; }
  }
}

// ---------------- SwiGLU elementwise ----------------
__global__ void swiglu_expert_k(const ushort_t* __restrict__ gu, ushort_t* __restrict__ hid){
  long qd = (long)blockIdx.x * 256 + threadIdx.x;
  long r = qd / (I_DIM / 8); int ic = (int)(qd % (I_DIM / 8)) * 8;
  const ushort_t* g = gu + r * I2_DIM + ic;
  u16x8 gv = *(const u16x8*)g;
  u16x8 uv = *(const u16x8*)(g + I_DIM);
  u16x8 ov;
  #pragma unroll
  for (int i = 0; i < 8; i++)
    ov[i] = f2bf(bf2f(uv[i]) * silu_f(bf2f(gv[i])));
  *(u16x8*)&hid[r * I_DIM + ic] = ov;
}

__global__ void swiglu_flat_k(ushort_t* __restrict__ sg, const ushort_t* __restrict__ si){
  long i = ((long)blockIdx.x * 256 + threadIdx.x) * 8;
  u16x8 g = *(const u16x8*)&sg[i];
  u16x8 s = *(const u16x8*)&si[i];
  u16x8 o;
  #pragma unroll
  for (int j = 0; j < 8; j++)
    o[j] = f2bf(bf2f(s[j]) * silu_f(bf2f(g[j])));
  *(u16x8*)&sg[i] = o;
}

// ======== R8 GEMM core: 128x128 / BK=32 / 4 waves, 3-buffer counted-vmcnt, asm ds_read ========
template<int MODE>
static __device__ __forceinline__ void gemm3_body(
    const ushort_t* __restrict__ A, const ushort_t* __restrict__ Bt,
    const ushort_t* __restrict__ Bt2, ushort_t* __restrict__ Cb,
    int K, int lda, int ldbt, int ldc, int mb,
    const int* __restrict__ counts, const int* __restrict__ bases,
    const int* __restrict__ lists, const float* __restrict__ probs,
    const float* __restrict__ svec, float* __restrict__ outp, long bstride){
  int z = blockIdx.z;
  int cnt = T_TOK;
  const ushort_t* Ab = A;
  const ushort_t* Bb = Bt;
  long rbase = 0;
  if constexpr (MODE == 0){ if (z){ Bb = Bt2; Cb += (long)T_TOK * ldc; } }
  if constexpr (MODE == 1){ cnt = counts[z]; rbase = bases[z]; Bb += (long)z * bstride; }
  if constexpr (MODE == 2){ cnt = counts[z]; Ab += (long)bases[z] * lda; Bb += (long)z * bstride; }

  int kb = K / gridDim.y;          // MODE 3 K-split; others gridDim.y==1
  int kbase = blockIdx.y * kb;
  Ab += kbase;
  Bb += kbase;                     // Bt is [N][K], k fastest

  // bijective XCD-chunked swizzle (m204)
  int nwg = gridDim.x;
  int wgo = blockIdx.x;
  int q = nwg >> 3, r = nwg & 7;
  int xcd = wgo & 7, idx = wgo >> 3;
  int wg = (xcd < r ? xcd * (q + 1) : r * (q + 1) + (xcd - r) * q) + idx;
  int m0 = (wg % mb) * 128;
  if (m0 >= cnt) return;
  int n0 = (wg / mb) * 128;

  __shared__ ushort_t lds[3 * 8192];     // 3 bufs x (A 4096 + B 4096) elems = 48 KiB
  unsigned lbase = (unsigned)(size_t)(__attribute__((address_space(3))) ushort_t*)lds;

  int tid = threadIdx.x;
  int lane = tid & 63;
  int wv = tid >> 6;        // 4 waves
  int wm = wv >> 1;
  int wn = wv & 1;

  int srow = lane >> 2;
  int sslot = ((lane & 3) ^ (srow & 3)) * 8;
  long aoff[2], boff[2];
  #pragma unroll
  for (int c = 0; c < 2; c++){
    int mr = wv * 32 + c * 16 + srow;
    int grow;
    if constexpr (MODE == 1){
      int j = m0 + mr; if (j >= cnt) j = cnt - 1;
      grow = lists[z * T_TOK + j];
    } else {
      grow = m0 + mr;
    }
    aoff[c] = (long)grow * lda + sslot;
    boff[c] = (long)(n0 + mr) * ldbt + sslot;
  }

  auto stage = [&](int t, int buf){
    long ko = (long)t * 32;
    ushort_t* dA = lds + buf * 8192 + wv * 1024;
    ushort_t* dB = dA + 4096;
    gld16(Ab + aoff[0] + ko, dA);
    gld16(Ab + aoff[1] + ko, dA + 512);
    gld16(Bb + boff[0] + ko, dB);
    gld16(Bb + boff[1] + ko, dB + 512);
  };

  f32x4 zero = {0.f, 0.f, 0.f, 0.f};
  f32x4 acc[4][4];
  #pragma unroll
  for (int i = 0; i < 4; i++)
    #pragma unroll
    for (int j = 0; j < 4; j++) acc[i][j] = zero;

  int fr = lane & 15;
  int kg = lane >> 4;
  unsigned ps = (unsigned)((kg ^ (fr & 3)) << 4);
  unsigned aoffb = (unsigned)((wm * 64 + fr) * 64) + ps;
  unsigned boffb = 8192u + (unsigned)((wn * 64 + fr) * 64) + ps;

  int nt = kb >> 5;
  stage(0, 0);
  __builtin_amdgcn_sched_barrier(0);
  stage(1, 1);

  int rb = 0, sb = 2;
  for (int t = 0; t < nt; t++){
    if (t + 2 < nt) asm volatile("s_waitcnt vmcnt(4)" ::: "memory");
    else            asm volatile("s_waitcnt vmcnt(0)" ::: "memory");
    __builtin_amdgcn_s_barrier();
    __builtin_amdgcn_sched_barrier(0);
    unsigned bufb = lbase + (unsigned)rb * 16384u;
    bf16x8 af[4], bg[4];
    #pragma unroll
    for (int f = 0; f < 4; f++){
      af[f] = dsr128(bufb + aoffb + f * 1024u);
      bg[f] = dsr128(bufb + boffb + f * 1024u);
    }
    __builtin_amdgcn_sched_barrier(0);
    if (t + 2 < nt) stage(t + 2, sb);
    asm volatile("s_waitcnt lgkmcnt(0)" ::: "memory");
    __builtin_amdgcn_sched_barrier(0);
    #pragma unroll
    for (int fm = 0; fm < 4; fm++)
      #pragma unroll
      for (int fn = 0; fn < 4; fn++)
        acc[fm][fn] = __builtin_amdgcn_mfma_f32_16x16x32_bf16(af[fm], bg[fn], acc[fm][fn], 0, 0, 0);
    rb = (rb == 2) ? 0 : rb + 1;
    sb = (sb == 2) ? 0 : sb + 1;
  }

  int colb = n0 + wn * 64 + (lane & 15);
  int rowb = m0 + wm * 64 + (lane >> 4) * 4;
  #pragma unroll
  for (int fm = 0; fm < 4; fm++){
    #pragma unroll
    for (int fn = 0; fn < 4; fn++){
      f32x4 v = acc[fm][fn];
      int col = colb + fn * 16;
      #pragma unroll
      for (int rr = 0; rr < 4; rr++){
        int m = rowb + fm * 16 + rr;
        if constexpr (MODE == 0){
          Cb[(long)m * ldc + col] = f2bf(v[rr]);
        } else if constexpr (MODE == 1){
          if (m < cnt) Cb[(rbase + m) * (long)ldc + col] = f2bf(v[rr]);
        } else if constexpr (MODE == 2){
          if (m < cnt){
            int tok = lists[z * T_TOK + m];
            float pp = probs[z * T_TOK + m];
            atomicAdd(outp + (long)tok * ldc + col, pp * v[rr]);
          }
        } else {
          atomicAdd(outp + (long)m * ldc + col, svec[m] * v[rr]);
        }
      }
    }
  }
}

// distinct names so rocprof top-k localizes cost per mode
#define GEMM_ARGS const ushort_t* A, const ushort_t* Bt, const ushort_t* Bt2, ushort_t* Cb, \
    int K, int lda, int ldbt, int ldc, int mb, const int* counts, const int* bases, \
    const int* lists, const float* probs, const float* svec, float* outp, long bstride
#define GEMM_PASS A, Bt, Bt2, Cb, K, lda, ldbt, ldc, mb, counts, bases, lists, probs, svec, outp, bstride

__global__ __launch_bounds__(256) void g_shared_gi(GEMM_ARGS){ gemm3_body<0>(GEMM_PASS); }
__global__ __launch_bounds__(256) void g_shared_out(GEMM_ARGS){ gemm3_body<3>(GEMM_PASS); }
__global__ __launch_bounds__(256) void g_expert_gu(GEMM_ARGS){ gemm3_body<1>(GEMM_PASS); }
__global__ __launch_bounds__(256) void g_expert_out(GEMM_ARGS){ gemm3_body<2>(GEMM_PASS); }

extern "C" void kernel_launch(void* const* d_in, const int* in_sizes, int n_in,
                              void* d_out, int out_size, void* d_ws, size_t ws_size,
                              hipStream_t stream){
  const float* x    = (const float*)d_in[0];
  const float* rw   = (const float*)d_in[1];
  const float* wgu  = (const float*)d_in[2];
  const float* wout = (const float*)d_in[3];
  const float* wsg  = (const float*)d_in[4];
  const float* wsi  = (const float*)d_in[5];
  const float* wso  = (const float*)d_in[6];
  const float* sgw  = (const float*)d_in[7];

  float* out = (float*)d_out;
  float* logits = out + (size_t)T_TOK * H_DIM;

  char* w = (char*)d_ws;
  auto alloc = [&](size_t b){ char* p = w; w += (b + 255) & ~(size_t)255; return p; };
  ushort_t* xb     = (ushort_t*)alloc((size_t)T_TOK * H_DIM * 2);
  ushort_t* wgu_t  = (ushort_t*)alloc((size_t)NEXP * I2_DIM * H_DIM * 2);
  ushort_t* wout_t = (ushort_t*)alloc((size_t)NEXP * H_DIM * I_DIM * 2);
  ushort_t* wsg_t  = (ushort_t*)alloc((size_t)IS_DIM * H_DIM * 2);
  ushort_t* wsi_t  = (ushort_t*)alloc((size_t)IS_DIM * H_DIM * 2);
  ushort_t* wso_t  = (ushort_t*)alloc((size_t)H_DIM * IS_DIM * 2);
  ushort_t* sgr    = (ushort_t*)alloc((size_t)2 * T_TOK * IS_DIM * 2);
  ushort_t* sir    = sgr + (size_t)T_TOK * IS_DIM;
  ushort_t* gu     = (ushort_t*)alloc((size_t)MAXROWS * I2_DIM * 2);
  ushort_t* hid    = (ushort_t*)alloc((size_t)MAXROWS * I_DIM * 2);
  int*   counts = (int*)alloc(64);
  int*   bases  = (int*)alloc(64);
  int*   lists  = (int*)alloc((size_t)NEXP * T_TOK * 4);
  float* probs  = (float*)alloc((size_t)NEXP * T_TOK * 4);
  float* sgmul  = (float*)alloc((size_t)T_TOK * 4);

  hipMemsetAsync(counts, 0, 64, stream);
  hipMemsetAsync(out, 0, (size_t)T_TOK * H_DIM * sizeof(float), stream);

  transpose_all_k<<<TR_TOT, 256, 0, stream>>>(wgu, wout, wsg, wsi, wso,
                                              wgu_t, wout_t, wsg_t, wsi_t, wso_t);
  router_k<<<512, 256, 0, stream>>>(x, rw, sgw, logits, counts, lists, probs, sgmul, xb);
  bases_k<<<1, 64, 0, stream>>>(counts, bases);

  // shared expert: gate & inter in one launch (z selects weight)
  g_shared_gi<<<dim3((T_TOK/128) * (IS_DIM/128), 1, 2), 256, 0, stream>>>(
      xb, wsg_t, wsi_t, sgr, H_DIM, H_DIM, H_DIM, IS_DIM, T_TOK/128,
      nullptr, nullptr, nullptr, nullptr, nullptr, nullptr, 0);
  swiglu_flat_k<<<(T_TOK * (IS_DIM/8)) / 256, 256, 0, stream>>>(sgr, sir);
  // shared out-projection, K-split x4, atomic accumulate into zeroed out
  g_shared_out<<<dim3((T_TOK/128) * (H_DIM/128), 4, 1), 256, 0, stream>>>(
      sgr, wso_t, nullptr, nullptr, IS_DIM, IS_DIM, IS_DIM, H_DIM, T_TOK/128,
      nullptr, nullptr, nullptr, nullptr, sgmul, out, 0);

  // sparse routed experts (atomic add on top of shared output)
  g_expert_gu<<<dim3((T_TOK/128) * (I2_DIM/128), 1, NEXP), 256, 0, stream>>>(
      xb, wgu_t, nullptr, gu, H_DIM, H_DIM, H_DIM, I2_DIM, T_TOK/128,
      counts, bases, lists, probs, nullptr, nullptr, (long)I2_DIM * H_DIM);
  swiglu_expert_k<<<((long)MAXROWS * (I_DIM/8)) / 256, 256, 0, stream>>>(gu, hid);
  g_expert_out<<<dim3((T_TOK/128) * (H_DIM/128), 1, NEXP), 256, 0, stream>>>(
      hid, wout_t, nullptr, nullptr, I_DIM, I_DIM, I_DIM, H_DIM, T_TOK/128,
      counts, bases, lists, probs, nullptr, out, (long)I_DIM * H_DIM);

  (void)in_sizes; (void)n_in; (void)out_size; (void)ws_size;
}

// Round 15
// 735.072 us; speedup vs baseline: 1.1734x; 1.0591x over previous
//
#include <hip/hip_runtime.h>
#include <math.h>

typedef __attribute__((ext_vector_type(4))) float f32x4;
typedef __attribute__((ext_vector_type(2))) unsigned int u32x2;
typedef __attribute__((ext_vector_type(4))) unsigned int u32x4;
typedef __attribute__((ext_vector_type(8))) unsigned short u16x8;
typedef __attribute__((ext_vector_type(8))) __bf16 bf16x8;
typedef unsigned short ushort_t;

#define H_DIM 2048
#define T_TOK 2048
#define NEXP 16
#define I_DIM 1408
#define I2_DIM 2816
#define IS_DIM 5632
#define MAXROWS 6144

static __device__ __forceinline__ unsigned short f2bf(float f){
  union { float f; unsigned u; } v; v.f = f;
  unsigned r = v.u + 0x7FFFu + ((v.u >> 16) & 1u);
  return (unsigned short)(r >> 16);
}
static __device__ __forceinline__ float bf2f(unsigned short h){
  union { unsigned u; float f; } v; v.u = ((unsigned)h) << 16;
  return v.f;
}
static __device__ __forceinline__ float silu_f(float x){ return x / (1.f + __expf(-x)); }

static __device__ __forceinline__ void gld16(const ushort_t* g, ushort_t* l){
  __builtin_amdgcn_global_load_lds(
      (const __attribute__((address_space(1))) unsigned int*)g,
      (__attribute__((address_space(3))) unsigned int*)l, 16, 0, 0);
}
static __device__ __forceinline__ bf16x8 dsr128(unsigned byte_off){
  u32x4 r;
  asm volatile("ds_read_b128 %0, %1" : "=v"(r) : "v"(byte_off));
  return __builtin_bit_cast(bf16x8, r);
}

// bijective XCD-chunked swizzle over a sub-grid of nwg blocks (nwg % 8 == 0 everywhere here)
static __device__ __forceinline__ int swz_r(int nwg, int wgo){
  int q = nwg >> 3, r = nwg & 7;
  int xcd = wgo & 7, idx = wgo >> 3;
  return (xcd < r ? xcd * (q + 1) : r * (q + 1) + (xcd - r) * q) + idx;
}

// ---------------- transpose tile (128k x 64n), nontemporal I/O ----------------
static __device__ __forceinline__ void tr_tile(const float* __restrict__ in,
                                               ushort_t* __restrict__ out,
                                               int K, int N, int k0, int n0){
  __shared__ float tl[128][65];
  int t = threadIdx.x;             // 256
  int lr = t >> 4;
  int lc = t & 15;
  #pragma unroll
  for (int p = 0; p < 8; p++){
    int row = p * 16 + lr;
    f32x4 v = __builtin_nontemporal_load((const f32x4*)&in[(long)(k0 + row) * N + n0 + lc * 4]);
    tl[row][lc*4 + 0] = v[0]; tl[row][lc*4 + 1] = v[1];
    tl[row][lc*4 + 2] = v[2]; tl[row][lc*4 + 3] = v[3];
  }
  __syncthreads();
  #pragma unroll
  for (int p = 0; p < 4; p++){
    int n = p * 16 + lr;
    int kc = lc * 8;
    union { ushort_t s[8]; u32x4 v; } pk;
    #pragma unroll
    for (int j = 0; j < 8; j++) pk.s[j] = f2bf(tl[kc + j][n]);
    __builtin_nontemporal_store(pk.v, (u32x4*)&out[(long)(n0 + n) * K + k0 + kc]);
  }
}

// segment offsets within the transpose sub-range (after the 512 router blocks)
#define TR_O1 11264
#define TR_O2 16896
#define TR_O3 18304
#define TR_O4 19712
#define TR_TOT 21120

// ---------------- merged: router (blocks 0..511) + all transposes ----------------
__global__ void k_tr_router(const float* __restrict__ x, const float* __restrict__ rw,
                            const float* __restrict__ sgw, float* __restrict__ logits,
                            int* __restrict__ counts, int* __restrict__ lists,
                            float* __restrict__ probs, float* __restrict__ sgmul,
                            ushort_t* __restrict__ xb,
                            const float* __restrict__ wgu, const float* __restrict__ wout,
                            const float* __restrict__ wsg, const float* __restrict__ wsi,
                            const float* __restrict__ wso,
                            ushort_t* __restrict__ wgu_t, ushort_t* __restrict__ wout_t,
                            ushort_t* __restrict__ wsg_t, ushort_t* __restrict__ wsi_t,
                            ushort_t* __restrict__ wso_t){
  int b = blockIdx.x;
  if (b < 512){
    // ---- router + fused x->bf16 cast ----
    int wid = threadIdx.x >> 6, lane = threadIdx.x & 63;
    int t = b * 4 + wid;
    const float* xr = x + (long)t * H_DIM;
    ushort_t* xbr = xb + (long)t * H_DIM;
    float acc[17];
    #pragma unroll
    for (int e = 0; e < 17; e++) acc[e] = 0.f;
    for (int h0 = lane * 4; h0 < H_DIM; h0 += 256){
      f32x4 xv = *(const f32x4*)&xr[h0];
      u32x2 pk;
      pk[0] = (unsigned)f2bf(xv[0]) | ((unsigned)f2bf(xv[1]) << 16);
      pk[1] = (unsigned)f2bf(xv[2]) | ((unsigned)f2bf(xv[3]) << 16);
      *(u32x2*)&xbr[h0] = pk;
      #pragma unroll
      for (int i = 0; i < 4; i++){
        float xs = xv[i];
        const float* wrow = rw + (long)(h0 + i) * NEXP;
        #pragma unroll
        for (int e = 0; e < 16; e++) acc[e] += xs * wrow[e];
        acc[16] += xs * sgw[h0 + i];
      }
    }
    #pragma unroll
    for (int e = 0; e < 17; e++)
      for (int off = 32; off >= 1; off >>= 1)
        acc[e] += __shfl_xor(acc[e], off);
    if (lane == 0){
      float* lo = logits + (long)t * NEXP;
      #pragma unroll
      for (int e = 0; e < 16; e++) lo[e] = acc[e];
      int e0 = 0;
      #pragma unroll
      for (int e = 1; e < 16; e++) if (acc[e] > acc[e0]) e0 = e;
      int e1 = (e0 == 0) ? 1 : 0;
      #pragma unroll
      for (int e = 0; e < 16; e++) if (e != e0 && acc[e] > acc[e1]) e1 = e;
      float d = acc[e1] - acc[e0];
      float ed = __expf(d);
      float p0 = 1.f / (1.f + ed);
      float p1 = ed / (1.f + ed);
      int pos0 = atomicAdd(&counts[e0], 1);
      lists[e0 * T_TOK + pos0] = t; probs[e0 * T_TOK + pos0] = p0;
      int pos1 = atomicAdd(&counts[e1], 1);
      lists[e1 * T_TOK + pos1] = t; probs[e1 * T_TOK + pos1] = p1;
      sgmul[t] = 1.f / (1.f + __expf(-acc[16]));
    }
    return;
  }
  int bb = b - 512;
  if (bb < TR_O1){
    int e = bb / 704, r = bb % 704;
    int ky = r / 44, nx = r % 44;
    long zo = (long)e * H_DIM * I2_DIM;
    tr_tile(wgu + zo, wgu_t + zo, H_DIM, I2_DIM, ky * 128, nx * 64);
  } else if (bb < TR_O2){
    int r = bb - TR_O1;
    int e = r / 352; r %= 352;
    int ky = r / 32, nx = r % 32;
    long zo = (long)e * I_DIM * H_DIM;
    tr_tile(wout + zo, wout_t + zo, I_DIM, H_DIM, ky * 128, nx * 64);
  } else if (bb < TR_O3){
    int r = bb - TR_O2;
    int ky = r / 88, nx = r % 88;
    tr_tile(wsg, wsg_t, H_DIM, IS_DIM, ky * 128, nx * 64);
  } else if (bb < TR_O4){
    int r = bb - TR_O3;
    int ky = r / 88, nx = r % 88;
    tr_tile(wsi, wsi_t, H_DIM, IS_DIM, ky * 128, nx * 64);
  } else {
    int r = bb - TR_O4;
    int ky = r / 32, nx = r % 32;
    tr_tile(wso, wso_t, IS_DIM, H_DIM, ky * 128, nx * 64);
  }
}

// ---------------- padded prefix bases (128-aligned) ----------------
__global__ void bases_k(const int* __restrict__ counts, int* __restrict__ bases){
  if (threadIdx.x == 0){
    int r = 0;
    for (int e = 0; e < NEXP; e++){ bases[e] = r; r += (counts[e] + 127) & ~127; }
  }
}

// ======== R8 GEMM core: 128x128 / BK=32 / 4 waves, 3-buffer counted-vmcnt, asm ds_read ========
// emode: 0 bf16 store; 1 masked bf16 store at rbase; 2 atomicAdd scprob scattered; 3 atomicAdd svec.
static __device__ __forceinline__ void gemm_core(
    const ushort_t* __restrict__ Ab, int lda,
    const ushort_t* __restrict__ Bb, int ldbt, int kb,
    int m0, int n0, int cnt, const int* __restrict__ gather, int emode,
    ushort_t* __restrict__ Cb, int ldc, long rbase,
    const int* __restrict__ sclist, const float* __restrict__ scprob,
    const float* __restrict__ svec, float* __restrict__ outp){
  __shared__ ushort_t lds[3 * 8192];     // 48 KiB
  unsigned lbase = (unsigned)(size_t)(__attribute__((address_space(3))) ushort_t*)lds;

  int tid = threadIdx.x;
  int lane = tid & 63;
  int wv = tid >> 6;
  int wm = wv >> 1;
  int wn = wv & 1;

  int srow = lane >> 2;
  int sslot = ((lane & 3) ^ (srow & 3)) * 8;
  long aoff[2], boff[2];
  #pragma unroll
  for (int c = 0; c < 2; c++){
    int mr = wv * 32 + c * 16 + srow;
    int grow;
    if (gather){
      int j = m0 + mr; if (j >= cnt) j = cnt - 1;
      grow = gather[j];
    } else {
      grow = m0 + mr;
    }
    aoff[c] = (long)grow * lda + sslot;
    boff[c] = (long)(n0 + mr) * ldbt + sslot;
  }

  auto stage = [&](int t, int buf){
    long ko = (long)t * 32;
    ushort_t* dA = lds + buf * 8192 + wv * 1024;
    ushort_t* dB = dA + 4096;
    gld16(Ab + aoff[0] + ko, dA);
    gld16(Ab + aoff[1] + ko, dA + 512);
    gld16(Bb + boff[0] + ko, dB);
    gld16(Bb + boff[1] + ko, dB + 512);
  };

  f32x4 zero = {0.f, 0.f, 0.f, 0.f};
  f32x4 acc[4][4];
  #pragma unroll
  for (int i = 0; i < 4; i++)
    #pragma unroll
    for (int j = 0; j < 4; j++) acc[i][j] = zero;

  int fr = lane & 15;
  int kg = lane >> 4;
  unsigned ps = (unsigned)((kg ^ (fr & 3)) << 4);
  unsigned aoffb = (unsigned)((wm * 64 + fr) * 64) + ps;
  unsigned boffb = 8192u + (unsigned)((wn * 64 + fr) * 64) + ps;

  int nt = kb >> 5;
  stage(0, 0);
  __builtin_amdgcn_sched_barrier(0);
  stage(1, 1);

  int rb = 0, sb = 2;
  for (int t = 0; t < nt; t++){
    if (t + 2 < nt) asm volatile("s_waitcnt vmcnt(4)" ::: "memory");
    else            asm volatile("s_waitcnt vmcnt(0)" ::: "memory");
    __builtin_amdgcn_s_barrier();
    __builtin_amdgcn_sched_barrier(0);
    unsigned bufb = lbase + (unsigned)rb * 16384u;
    bf16x8 af[4], bg[4];
    #pragma unroll
    for (int f = 0; f < 4; f++){
      af[f] = dsr128(bufb + aoffb + f * 1024u);
      bg[f] = dsr128(bufb + boffb + f * 1024u);
    }
    __builtin_amdgcn_sched_barrier(0);
    if (t + 2 < nt) stage(t + 2, sb);
    asm volatile("s_waitcnt lgkmcnt(0)" ::: "memory");
    __builtin_amdgcn_sched_barrier(0);
    #pragma unroll
    for (int fm = 0; fm < 4; fm++)
      #pragma unroll
      for (int fn = 0; fn < 4; fn++)
        acc[fm][fn] = __builtin_amdgcn_mfma_f32_16x16x32_bf16(af[fm], bg[fn], acc[fm][fn], 0, 0, 0);
    rb = (rb == 2) ? 0 : rb + 1;
    sb = (sb == 2) ? 0 : sb + 1;
  }

  int colb = n0 + wn * 64 + (lane & 15);
  int rowb = m0 + wm * 64 + (lane >> 4) * 4;
  #pragma unroll
  for (int fm = 0; fm < 4; fm++){
    #pragma unroll
    for (int fn = 0; fn < 4; fn++){
      f32x4 v = acc[fm][fn];
      int col = colb + fn * 16;
      #pragma unroll
      for (int rr = 0; rr < 4; rr++){
        int m = rowb + fm * 16 + rr;
        if (emode == 0){
          Cb[(long)m * ldc + col] = f2bf(v[rr]);
        } else if (emode == 1){
          if (m < cnt) Cb[(rbase + m) * (long)ldc + col] = f2bf(v[rr]);
        } else if (emode == 2){
          if (m < cnt){
            int tok = sclist[m];
            atomicAdd(outp + (long)tok * ldc + col, scprob[m] * v[rr]);
          }
        } else {
          atomicAdd(outp + (long)m * ldc + col, svec[m] * v[rr]);
        }
      }
    }
  }
}

// ---- shared gate+inter (z in {0,1}), grid x = 704 ----
__global__ __launch_bounds__(256) void g_shared_gi(
    const ushort_t* xb, const ushort_t* wsg_t, const ushort_t* wsi_t, ushort_t* sgr){
  int z = blockIdx.z;
  int wg = swz_r(704, blockIdx.x);
  int m0 = (wg % 16) * 128, n0 = (wg / 16) * 128;
  gemm_core(xb, H_DIM, (z ? wsi_t : wsg_t), H_DIM, H_DIM, m0, n0, T_TOK,
            nullptr, 0, sgr + (size_t)z * T_TOK * IS_DIM, IS_DIM, 0,
            nullptr, nullptr, nullptr, nullptr);
}

// ---- merged: expert gate_up (blocks 0..5631) + shared swiglu_flat (5632..11263) ----
__global__ __launch_bounds__(256) void k_gu_flat(
    const ushort_t* xb, const ushort_t* wgu_t, ushort_t* gu,
    const int* counts, const int* bases, const int* lists,
    ushort_t* sg, const ushort_t* si){
  int b = blockIdx.x;
  if (b < 5632){
    int e = b / 352, r = b % 352;
    int wr = swz_r(352, r);
    int m0 = (wr % 16) * 128, n0 = (wr / 16) * 128;
    int cnt = counts[e];
    if (m0 >= cnt) return;
    gemm_core(xb, H_DIM, wgu_t + (size_t)e * I2_DIM * H_DIM, H_DIM, H_DIM,
              m0, n0, cnt, lists + e * T_TOK, 1, gu, I2_DIM, bases[e],
              nullptr, nullptr, nullptr, nullptr);
  } else {
    long i = ((long)(b - 5632) * 256 + threadIdx.x) * 8;
    u16x8 g = *(const u16x8*)&sg[i];
    u16x8 s = *(const u16x8*)&si[i];
    u16x8 o;
    #pragma unroll
    for (int j = 0; j < 8; j++)
      o[j] = f2bf(bf2f(s[j]) * silu_f(bf2f(g[j])));
    *(u16x8*)&sg[i] = o;
  }
}

// ---- merged: shared out-proj K-split x4 (blocks 0..1023) + expert swiglu (1024..5247) ----
__global__ __launch_bounds__(256) void k_so_se(
    const ushort_t* sgr, const ushort_t* wso_t, const float* sgmul, float* out,
    const ushort_t* gu, ushort_t* hid){
  int b = blockIdx.x;
  if (b < 1024){
    int kq = b >> 8, r = b & 255;
    int wr = swz_r(256, r);
    int m0 = (wr % 16) * 128, n0 = (wr / 16) * 128;
    gemm_core(sgr + kq * (IS_DIM/4), IS_DIM, wso_t + kq * (IS_DIM/4), IS_DIM, IS_DIM/4,
              m0, n0, T_TOK, nullptr, 3, nullptr, H_DIM, 0,
              nullptr, nullptr, sgmul, out);
  } else {
    long qd = (long)(b - 1024) * 256 + threadIdx.x;
    long r = qd / (I_DIM / 8); int ic = (int)(qd % (I_DIM / 8)) * 8;
    const ushort_t* g = gu + r * I2_DIM + ic;
    u16x8 gv = *(const u16x8*)g;
    u16x8 uv = *(const u16x8*)(g + I_DIM);
    u16x8 ov;
    #pragma unroll
    for (int i = 0; i < 8; i++)
      ov[i] = f2bf(bf2f(uv[i]) * silu_f(bf2f(gv[i])));
    *(u16x8*)&hid[r * I_DIM + ic] = ov;
  }
}

// ---- expert out-projection: 16 experts x 256 blocks ----
__global__ __launch_bounds__(256) void k_eo(
    const ushort_t* hid, const ushort_t* wout_t,
    const int* counts, const int* bases, const int* lists, const float* probs,
    float* out){
  int b = blockIdx.x;
  int e = b >> 8, r = b & 255;
  int wr = swz_r(256, r);
  int m0 = (wr % 16) * 128, n0 = (wr / 16) * 128;
  int cnt = counts[e];
  if (m0 >= cnt) return;
  gemm_core(hid + (size_t)bases[e] * I_DIM, I_DIM,
            wout_t + (size_t)e * H_DIM * I_DIM, I_DIM, I_DIM,
            m0, n0, cnt, nullptr, 2, nullptr, H_DIM, 0,
            lists + e * T_TOK, probs + e * T_TOK, nullptr, out);
}

extern "C" void kernel_launch(void* const* d_in, const int* in_sizes, int n_in,
                              void* d_out, int out_size, void* d_ws, size_t ws_size,
                              hipStream_t stream){
  const float* x    = (const float*)d_in[0];
  const float* rw   = (const float*)d_in[1];
  const float* wgu  = (const float*)d_in[2];
  const float* wout = (const float*)d_in[3];
  const float* wsg  = (const float*)d_in[4];
  const float* wsi  = (const float*)d_in[5];
  const float* wso  = (const float*)d_in[6];
  const float* sgw  = (const float*)d_in[7];

  float* out = (float*)d_out;
  float* logits = out + (size_t)T_TOK * H_DIM;

  char* w = (char*)d_ws;
  auto alloc = [&](size_t b){ char* p = w; w += (b + 255) & ~(size_t)255; return p; };
  ushort_t* xb     = (ushort_t*)alloc((size_t)T_TOK * H_DIM * 2);
  ushort_t* wgu_t  = (ushort_t*)alloc((size_t)NEXP * I2_DIM * H_DIM * 2);
  ushort_t* wout_t = (ushort_t*)alloc((size_t)NEXP * H_DIM * I_DIM * 2);
  ushort_t* wsg_t  = (ushort_t*)alloc((size_t)IS_DIM * H_DIM * 2);
  ushort_t* wsi_t  = (ushort_t*)alloc((size_t)IS_DIM * H_DIM * 2);
  ushort_t* wso_t  = (ushort_t*)alloc((size_t)H_DIM * IS_DIM * 2);
  ushort_t* sgr    = (ushort_t*)alloc((size_t)2 * T_TOK * IS_DIM * 2);
  ushort_t* sir    = sgr + (size_t)T_TOK * IS_DIM;
  ushort_t* gu     = (ushort_t*)alloc((size_t)MAXROWS * I2_DIM * 2);
  ushort_t* hid    = (ushort_t*)alloc((size_t)MAXROWS * I_DIM * 2);
  int*   counts = (int*)alloc(64);
  int*   bases  = (int*)alloc(64);
  int*   lists  = (int*)alloc((size_t)NEXP * T_TOK * 4);
  float* probs  = (float*)alloc((size_t)NEXP * T_TOK * 4);
  float* sgmul  = (float*)alloc((size_t)T_TOK * 4);

  hipMemsetAsync(counts, 0, 64, stream);
  hipMemsetAsync(out, 0, (size_t)T_TOK * H_DIM * sizeof(float), stream);

  // router (hidden) + all weight transposes
  k_tr_router<<<512 + TR_TOT, 256, 0, stream>>>(
      x, rw, sgw, logits, counts, lists, probs, sgmul, xb,
      wgu, wout, wsg, wsi, wso, wgu_t, wout_t, wsg_t, wsi_t, wso_t);
  bases_k<<<1, 64, 0, stream>>>(counts, bases);

  // shared gate & inter
  g_shared_gi<<<dim3(704, 1, 2), 256, 0, stream>>>(xb, wsg_t, wsi_t, sgr);

  // expert gate_up (pole) + shared swiglu (hidden)
  k_gu_flat<<<5632 + 5632, 256, 0, stream>>>(xb, wgu_t, gu, counts, bases, lists, sgr, sir);

  // shared out-projection (pole) + expert swiglu (hidden)
  k_so_se<<<1024 + 4224, 256, 0, stream>>>(sgr, wso_t, sgmul, out, gu, hid);

  // expert out-projection
  k_eo<<<NEXP * 256, 256, 0, stream>>>(hid, wout_t, counts, bases, lists, probs, out);

  (void)in_sizes; (void)n_in; (void)out_size; (void)ws_size;
}

// Round 16
// 707.860 us; speedup vs baseline: 1.2185x; 1.0384x over previous
//
#include <hip/hip_runtime.h>
#include <math.h>

typedef __attribute__((ext_vector_type(4))) float f32x4;
typedef __attribute__((ext_vector_type(2))) unsigned int u32x2;
typedef __attribute__((ext_vector_type(4))) unsigned int u32x4;
typedef __attribute__((ext_vector_type(8))) unsigned short u16x8;
typedef __attribute__((ext_vector_type(8))) __bf16 bf16x8;
typedef unsigned short ushort_t;

#define H_DIM 2048
#define T_TOK 2048
#define NEXP 16
#define I_DIM 1408
#define I2_DIM 2816
#define IS_DIM 5632
#define MAXROWS 6144

static __device__ __forceinline__ unsigned short f2bf(float f){
  union { float f; unsigned u; } v; v.f = f;
  unsigned r = v.u + 0x7FFFu + ((v.u >> 16) & 1u);
  return (unsigned short)(r >> 16);
}
static __device__ __forceinline__ float bf2f(unsigned short h){
  union { unsigned u; float f; } v; v.u = ((unsigned)h) << 16;
  return v.f;
}
static __device__ __forceinline__ float silu_f(float x){ return x / (1.f + __expf(-x)); }

static __device__ __forceinline__ void gld16(const ushort_t* g, ushort_t* l){
  __builtin_amdgcn_global_load_lds(
      (const __attribute__((address_space(1))) unsigned int*)g,
      (__attribute__((address_space(3))) unsigned int*)l, 16, 0, 0);
}
static __device__ __forceinline__ bf16x8 dsr128(unsigned byte_off){
  u32x4 r;
  asm volatile("ds_read_b128 %0, %1" : "=v"(r) : "v"(byte_off));
  return __builtin_bit_cast(bf16x8, r);
}

// bijective XCD-chunked swizzle over nwg blocks (nwg % 8 == 0 everywhere here)
static __device__ __forceinline__ int swz_r(int nwg, int wgo){
  int q = nwg >> 3, r = nwg & 7;
  int xcd = wgo & 7, idx = wgo >> 3;
  return (xcd < r ? xcd * (q + 1) : r * (q + 1) + (xcd - r) * q) + idx;
}

// inline padded-prefix base for expert e (counts already final)
static __device__ __forceinline__ long base_of(const int* __restrict__ counts, int e){
  long r = 0;
  for (int i = 0; i < e; i++) r += (counts[i] + 127) & ~127;
  return r;
}

// ---------------- transpose tile (128k x 64n); shared passed in ----------------
static __device__ __forceinline__ void tr_tile(float (*tl)[65],
                                               const float* __restrict__ in,
                                               ushort_t* __restrict__ out,
                                               int K, int N, int k0, int n0){
  int t = threadIdx.x;             // 256
  int lr = t >> 4;
  int lc = t & 15;
  #pragma unroll
  for (int p = 0; p < 8; p++){
    int row = p * 16 + lr;
    f32x4 v = *(const f32x4*)&in[(long)(k0 + row) * N + n0 + lc * 4];
    tl[row][lc*4 + 0] = v[0]; tl[row][lc*4 + 1] = v[1];
    tl[row][lc*4 + 2] = v[2]; tl[row][lc*4 + 3] = v[3];
  }
  __syncthreads();
  #pragma unroll
  for (int p = 0; p < 4; p++){
    int n = p * 16 + lr;
    int kc = lc * 8;
    union { ushort_t s[8]; u32x4 v; } pk;
    #pragma unroll
    for (int j = 0; j < 8; j++) pk.s[j] = f2bf(tl[kc + j][n]);
    *(u32x4*)&out[(long)(n0 + n) * K + k0 + kc] = pk.v;
  }
}

// ======== R8 GEMM core: 128x128 / BK=32 / 4 waves, 3-buffer counted-vmcnt, asm ds_read ========
// emode: 0 bf16 store; 1 masked bf16 store at rbase; 2 atomicAdd scprob scattered; 3 atomicAdd svec.
static __device__ __forceinline__ void gemm_core(
    ushort_t* __restrict__ lds,          // >= 3*8192 elems (48 KiB)
    const ushort_t* __restrict__ Ab, int lda,
    const ushort_t* __restrict__ Bb, int ldbt, int kb,
    int m0, int n0, int cnt, const int* __restrict__ gather, int emode,
    ushort_t* __restrict__ Cb, int ldc, long rbase,
    const int* __restrict__ sclist, const float* __restrict__ scprob,
    const float* __restrict__ svec, float* __restrict__ outp){
  unsigned lbase = (unsigned)(size_t)(__attribute__((address_space(3))) ushort_t*)lds;

  int tid = threadIdx.x;
  int lane = tid & 63;
  int wv = tid >> 6;
  int wm = wv >> 1;
  int wn = wv & 1;

  int srow = lane >> 2;
  int sslot = ((lane & 3) ^ (srow & 3)) * 8;
  long aoff[2], boff[2];
  #pragma unroll
  for (int c = 0; c < 2; c++){
    int mr = wv * 32 + c * 16 + srow;
    int grow;
    if (gather){
      int j = m0 + mr; if (j >= cnt) j = cnt - 1;
      grow = gather[j];
    } else {
      grow = m0 + mr;
    }
    aoff[c] = (long)grow * lda + sslot;
    boff[c] = (long)(n0 + mr) * ldbt + sslot;
  }

  auto stage = [&](int t, int buf){
    long ko = (long)t * 32;
    ushort_t* dA = lds + buf * 8192 + wv * 1024;
    ushort_t* dB = dA + 4096;
    gld16(Ab + aoff[0] + ko, dA);
    gld16(Ab + aoff[1] + ko, dA + 512);
    gld16(Bb + boff[0] + ko, dB);
    gld16(Bb + boff[1] + ko, dB + 512);
  };

  f32x4 zero = {0.f, 0.f, 0.f, 0.f};
  f32x4 acc[4][4];
  #pragma unroll
  for (int i = 0; i < 4; i++)
    #pragma unroll
    for (int j = 0; j < 4; j++) acc[i][j] = zero;

  int fr = lane & 15;
  int kg = lane >> 4;
  unsigned ps = (unsigned)((kg ^ (fr & 3)) << 4);
  unsigned aoffb = (unsigned)((wm * 64 + fr) * 64) + ps;
  unsigned boffb = 8192u + (unsigned)((wn * 64 + fr) * 64) + ps;

  int nt = kb >> 5;
  stage(0, 0);
  __builtin_amdgcn_sched_barrier(0);
  stage(1, 1);

  int rb = 0, sb = 2;
  for (int t = 0; t < nt; t++){
    if (t + 2 < nt) asm volatile("s_waitcnt vmcnt(4)" ::: "memory");
    else            asm volatile("s_waitcnt vmcnt(0)" ::: "memory");
    __builtin_amdgcn_s_barrier();
    __builtin_amdgcn_sched_barrier(0);
    unsigned bufb = lbase + (unsigned)rb * 16384u;
    bf16x8 af[4], bg[4];
    #pragma unroll
    for (int f = 0; f < 4; f++){
      af[f] = dsr128(bufb + aoffb + f * 1024u);
      bg[f] = dsr128(bufb + boffb + f * 1024u);
    }
    __builtin_amdgcn_sched_barrier(0);
    if (t + 2 < nt) stage(t + 2, sb);
    asm volatile("s_waitcnt lgkmcnt(0)" ::: "memory");
    __builtin_amdgcn_sched_barrier(0);
    #pragma unroll
    for (int fm = 0; fm < 4; fm++)
      #pragma unroll
      for (int fn = 0; fn < 4; fn++)
        acc[fm][fn] = __builtin_amdgcn_mfma_f32_16x16x32_bf16(af[fm], bg[fn], acc[fm][fn], 0, 0, 0);
    rb = (rb == 2) ? 0 : rb + 1;
    sb = (sb == 2) ? 0 : sb + 1;
  }

  int colb = n0 + wn * 64 + (lane & 15);
  int rowb = m0 + wm * 64 + (lane >> 4) * 4;
  #pragma unroll
  for (int fm = 0; fm < 4; fm++){
    #pragma unroll
    for (int fn = 0; fn < 4; fn++){
      f32x4 v = acc[fm][fn];
      int col = colb + fn * 16;
      #pragma unroll
      for (int rr = 0; rr < 4; rr++){
        int m = rowb + fm * 16 + rr;
        if (emode == 0){
          Cb[(long)m * ldc + col] = f2bf(v[rr]);
        } else if (emode == 1){
          if (m < cnt) Cb[(rbase + m) * (long)ldc + col] = f2bf(v[rr]);
        } else if (emode == 2){
          if (m < cnt){
            int tok = sclist[m];
            atomicAdd(outp + (long)tok * ldc + col, scprob[m] * v[rr]);
          }
        } else {
          atomicAdd(outp + (long)m * ldc + col, svec[m] * v[rr]);
        }
      }
    }
  }
}

// ---------------- k_tr1: router (0..511) + wsg (512..1919) + wsi (1920..3327) + wso (3328..4735) --
__global__ void k_tr1(const float* __restrict__ x, const float* __restrict__ rw,
                      const float* __restrict__ sgw, float* __restrict__ logits,
                      int* __restrict__ counts, int* __restrict__ lists,
                      float* __restrict__ probs, float* __restrict__ sgmul,
                      ushort_t* __restrict__ xb,
                      const float* __restrict__ wsg, const float* __restrict__ wsi,
                      const float* __restrict__ wso,
                      ushort_t* __restrict__ wsg_t, ushort_t* __restrict__ wsi_t,
                      ushort_t* __restrict__ wso_t){
  __shared__ float tl[128][65];
  int b = blockIdx.x;
  if (b < 512){
    int wid = threadIdx.x >> 6, lane = threadIdx.x & 63;
    int t = b * 4 + wid;
    const float* xr = x + (long)t * H_DIM;
    ushort_t* xbr = xb + (long)t * H_DIM;
    float acc[17];
    #pragma unroll
    for (int e = 0; e < 17; e++) acc[e] = 0.f;
    for (int h0 = lane * 4; h0 < H_DIM; h0 += 256){
      f32x4 xv = *(const f32x4*)&xr[h0];
      u32x2 pk;
      pk[0] = (unsigned)f2bf(xv[0]) | ((unsigned)f2bf(xv[1]) << 16);
      pk[1] = (unsigned)f2bf(xv[2]) | ((unsigned)f2bf(xv[3]) << 16);
      *(u32x2*)&xbr[h0] = pk;
      #pragma unroll
      for (int i = 0; i < 4; i++){
        float xs = xv[i];
        const float* wrow = rw + (long)(h0 + i) * NEXP;
        #pragma unroll
        for (int e = 0; e < 16; e++) acc[e] += xs * wrow[e];
        acc[16] += xs * sgw[h0 + i];
      }
    }
    #pragma unroll
    for (int e = 0; e < 17; e++)
      for (int off = 32; off >= 1; off >>= 1)
        acc[e] += __shfl_xor(acc[e], off);
    if (lane == 0){
      float* lo = logits + (long)t * NEXP;
      #pragma unroll
      for (int e = 0; e < 16; e++) lo[e] = acc[e];
      int e0 = 0;
      #pragma unroll
      for (int e = 1; e < 16; e++) if (acc[e] > acc[e0]) e0 = e;
      int e1 = (e0 == 0) ? 1 : 0;
      #pragma unroll
      for (int e = 0; e < 16; e++) if (e != e0 && acc[e] > acc[e1]) e1 = e;
      float d = acc[e1] - acc[e0];
      float ed = __expf(d);
      float p0 = 1.f / (1.f + ed);
      float p1 = ed / (1.f + ed);
      int pos0 = atomicAdd(&counts[e0], 1);
      lists[e0 * T_TOK + pos0] = t; probs[e0 * T_TOK + pos0] = p0;
      int pos1 = atomicAdd(&counts[e1], 1);
      lists[e1 * T_TOK + pos1] = t; probs[e1 * T_TOK + pos1] = p1;
      sgmul[t] = 1.f / (1.f + __expf(-acc[16]));
    }
    return;
  }
  int bb = b - 512;
  if (bb < 1408){
    int ky = bb / 88, nx = bb % 88;
    tr_tile(tl, wsg, wsg_t, H_DIM, IS_DIM, ky * 128, nx * 64);
  } else if (bb < 2816){
    int r = bb - 1408;
    int ky = r / 88, nx = r % 88;
    tr_tile(tl, wsi, wsi_t, H_DIM, IS_DIM, ky * 128, nx * 64);
  } else {
    int r = bb - 2816;
    int ky = r / 32, nx = r % 32;
    tr_tile(tl, wso, wso_t, IS_DIM, H_DIM, ky * 128, nx * 64);
  }
}

// ---- k_gi_tr2: shared gate+inter GEMM (0..1407, dispatched first) + wgu/wout transposes ----
__global__ __launch_bounds__(256) void k_gi_tr2(
    const ushort_t* __restrict__ xb, const ushort_t* __restrict__ wsg_t,
    const ushort_t* __restrict__ wsi_t, ushort_t* __restrict__ sgr,
    const float* __restrict__ wgu, const float* __restrict__ wout,
    ushort_t* __restrict__ wgu_t, ushort_t* __restrict__ wout_t){
  __shared__ char smem[49152];           // union: gemm 48 KiB | tr 33.3 KiB
  int b = blockIdx.x;
  if (b < 1408){
    int z = b & 1;
    int wg = swz_r(704, b >> 1);
    int m0 = (wg % 16) * 128, n0 = (wg / 16) * 128;
    gemm_core((ushort_t*)smem, xb, H_DIM, (z ? wsi_t : wsg_t), H_DIM, H_DIM,
              m0, n0, T_TOK, nullptr, 0,
              sgr + (size_t)z * T_TOK * IS_DIM, IS_DIM, 0,
              nullptr, nullptr, nullptr, nullptr);
    return;
  }
  float (*tl)[65] = (float(*)[65])smem;
  int bb = b - 1408;
  if (bb < 11264){
    int e = bb / 704, r = bb % 704;
    int ky = r / 44, nx = r % 44;
    long zo = (long)e * H_DIM * I2_DIM;
    tr_tile(tl, wgu + zo, wgu_t + zo, H_DIM, I2_DIM, ky * 128, nx * 64);
  } else {
    int r = bb - 11264;
    int e = r / 352; r %= 352;
    int ky = r / 32, nx = r % 32;
    long zo = (long)e * I_DIM * H_DIM;
    tr_tile(tl, wout + zo, wout_t + zo, I_DIM, H_DIM, ky * 128, nx * 64);
  }
}

// ---- merged: expert gate_up (0..5631) + shared swiglu_flat (5632..11263) ----
__global__ __launch_bounds__(256) void k_gu_flat(
    const ushort_t* __restrict__ xb, const ushort_t* __restrict__ wgu_t,
    ushort_t* __restrict__ gu,
    const int* __restrict__ counts, const int* __restrict__ lists,
    ushort_t* __restrict__ sg, const ushort_t* __restrict__ si){
  int b = blockIdx.x;
  if (b < 5632){
    __shared__ ushort_t lds[3 * 8192];
    int e = b / 352, r = b % 352;
    int wr = swz_r(352, r);
    int m0 = (wr % 16) * 128, n0 = (wr / 16) * 128;
    int cnt = counts[e];
    if (m0 >= cnt) return;
    gemm_core(lds, xb, H_DIM, wgu_t + (size_t)e * I2_DIM * H_DIM, H_DIM, H_DIM,
              m0, n0, cnt, lists + e * T_TOK, 1, gu, I2_DIM, base_of(counts, e),
              nullptr, nullptr, nullptr, nullptr);
  } else {
    long i = ((long)(b - 5632) * 256 + threadIdx.x) * 8;
    u16x8 g = *(const u16x8*)&sg[i];
    u16x8 s = *(const u16x8*)&si[i];
    u16x8 o;
    #pragma unroll
    for (int j = 0; j < 8; j++)
      o[j] = f2bf(bf2f(s[j]) * silu_f(bf2f(g[j])));
    *(u16x8*)&sg[i] = o;
  }
}

// ---- merged: shared out-proj K-split x2 (0..511) + expert swiglu (512..4735) ----
__global__ __launch_bounds__(256) void k_so_se(
    const ushort_t* __restrict__ sgr, const ushort_t* __restrict__ wso_t,
    const float* __restrict__ sgmul, float* __restrict__ out,
    const ushort_t* __restrict__ gu, ushort_t* __restrict__ hid){
  int b = blockIdx.x;
  if (b < 512){
    __shared__ ushort_t lds[3 * 8192];
    int kq = b >> 8, r = b & 255;
    int wr = swz_r(256, r);
    int m0 = (wr % 16) * 128, n0 = (wr / 16) * 128;
    gemm_core(lds, sgr + kq * (IS_DIM/2), IS_DIM, wso_t + kq * (IS_DIM/2), IS_DIM, IS_DIM/2,
              m0, n0, T_TOK, nullptr, 3, nullptr, H_DIM, 0,
              nullptr, nullptr, sgmul, out);
  } else {
    long qd = (long)(b - 512) * 256 + threadIdx.x;
    long r = qd / (I_DIM / 8); int ic = (int)(qd % (I_DIM / 8)) * 8;
    const ushort_t* g = gu + r * I2_DIM + ic;
    u16x8 gv = *(const u16x8*)g;
    u16x8 uv = *(const u16x8*)(g + I_DIM);
    u16x8 ov;
    #pragma unroll
    for (int i = 0; i < 8; i++)
      ov[i] = f2bf(bf2f(uv[i]) * silu_f(bf2f(gv[i])));
    *(u16x8*)&hid[r * I_DIM + ic] = ov;
  }
}

// ---- expert out-projection: 16 experts x 256 blocks ----
__global__ __launch_bounds__(256) void k_eo(
    const ushort_t* __restrict__ hid, const ushort_t* __restrict__ wout_t,
    const int* __restrict__ counts, const int* __restrict__ lists,
    const float* __restrict__ probs, float* __restrict__ out){
  __shared__ ushort_t lds[3 * 8192];
  int b = blockIdx.x;
  int e = b >> 8, r = b & 255;
  int wr = swz_r(256, r);
  int m0 = (wr % 16) * 128, n0 = (wr / 16) * 128;
  int cnt = counts[e];
  if (m0 >= cnt) return;
  gemm_core(lds, hid + (size_t)base_of(counts, e) * I_DIM, I_DIM,
            wout_t + (size_t)e * H_DIM * I_DIM, I_DIM, I_DIM,
            m0, n0, cnt, nullptr, 2, nullptr, H_DIM, 0,
            lists + e * T_TOK, probs + e * T_TOK, nullptr, out);
}

extern "C" void kernel_launch(void* const* d_in, const int* in_sizes, int n_in,
                              void* d_out, int out_size, void* d_ws, size_t ws_size,
                              hipStream_t stream){
  const float* x    = (const float*)d_in[0];
  const float* rw   = (const float*)d_in[1];
  const float* wgu  = (const float*)d_in[2];
  const float* wout = (const float*)d_in[3];
  const float* wsg  = (const float*)d_in[4];
  const float* wsi  = (const float*)d_in[5];
  const float* wso  = (const float*)d_in[6];
  const float* sgw  = (const float*)d_in[7];

  float* out = (float*)d_out;
  float* logits = out + (size_t)T_TOK * H_DIM;

  char* w = (char*)d_ws;
  auto alloc = [&](size_t b){ char* p = w; w += (b + 255) & ~(size_t)255; return p; };
  ushort_t* xb     = (ushort_t*)alloc((size_t)T_TOK * H_DIM * 2);
  ushort_t* wgu_t  = (ushort_t*)alloc((size_t)NEXP * I2_DIM * H_DIM * 2);
  ushort_t* wout_t = (ushort_t*)alloc((size_t)NEXP * H_DIM * I_DIM * 2);
  ushort_t* wsg_t  = (ushort_t*)alloc((size_t)IS_DIM * H_DIM * 2);
  ushort_t* wsi_t  = (ushort_t*)alloc((size_t)IS_DIM * H_DIM * 2);
  ushort_t* wso_t  = (ushort_t*)alloc((size_t)H_DIM * IS_DIM * 2);
  ushort_t* sgr    = (ushort_t*)alloc((size_t)2 * T_TOK * IS_DIM * 2);
  ushort_t* sir    = sgr + (size_t)T_TOK * IS_DIM;
  ushort_t* gu     = (ushort_t*)alloc((size_t)MAXROWS * I2_DIM * 2);
  ushort_t* hid    = (ushort_t*)alloc((size_t)MAXROWS * I_DIM * 2);
  int*   counts = (int*)alloc(64);
  int*   lists  = (int*)alloc((size_t)NEXP * T_TOK * 4);
  float* probs  = (float*)alloc((size_t)NEXP * T_TOK * 4);
  float* sgmul  = (float*)alloc((size_t)T_TOK * 4);

  hipMemsetAsync(counts, 0, 64, stream);
  hipMemsetAsync(out, 0, (size_t)T_TOK * H_DIM * sizeof(float), stream);

  // router + shared-path weight transposes
  k_tr1<<<4736, 256, 0, stream>>>(x, rw, sgw, logits, counts, lists, probs, sgmul, xb,
                                  wsg, wsi, wso, wsg_t, wsi_t, wso_t);
  // shared gate/inter GEMM (first) overlapped with expert weight transposes
  k_gi_tr2<<<1408 + 16896, 256, 0, stream>>>(xb, wsg_t, wsi_t, sgr,
                                             wgu, wout, wgu_t, wout_t);
  // expert gate_up + shared swiglu
  k_gu_flat<<<5632 + 5632, 256, 0, stream>>>(xb, wgu_t, gu, counts, lists, sgr, sir);
  // shared out-projection (K-split x2) + expert swiglu
  k_so_se<<<512 + 4224, 256, 0, stream>>>(sgr, wso_t, sgmul, out, gu, hid);
  // expert out-projection
  k_eo<<<NEXP * 256, 256, 0, stream>>>(hid, wout_t, counts, lists, probs, out);

  (void)in_sizes; (void)n_in; (void)out_size; (void)ws_size;
}